// Round 2
// baseline (283.563 us; speedup 1.0000x reference)
//
#include <hip/hip_runtime.h>
#include <hip/hip_bf16.h>

typedef unsigned short ushort_t;
typedef short short8 __attribute__((ext_vector_type(8)));
typedef float f32x4 __attribute__((ext_vector_type(4)));

#define B_  2
#define S_  4096
#define D_  512
#define H_  8
#define HD_ 64
#define DK_ 256
#define TOPK_ 256
#define KSLOTS_ 512   // 2*TOPK_ slots (union of both batches' top-k)

__device__ __forceinline__ float bf2f(ushort_t u) {
    unsigned int b = ((unsigned int)u) << 16;
    float f;
    __builtin_memcpy(&f, &b, 4);
    return f;
}
__device__ __forceinline__ ushort_t f2bf(float f) {
    unsigned int b;
    __builtin_memcpy(&b, &f, 4);
    b = (b + 0x7FFFu + ((b >> 16) & 1u)) >> 16;
    return (ushort_t)b;
}

// ---------------------------------------------------------------------------
// fp32 -> bf16 pack, 8 elements/thread. total = 8192*512 elements.
// ---------------------------------------------------------------------------
__global__ __launch_bounds__(256) void pack_bf16_k(
    const float* __restrict__ in, ushort_t* __restrict__ out)
{
    const long i = ((long)blockIdx.x * 256 + threadIdx.x) * 8;
    const float4 a = *(const float4*)(in + i);
    const float4 b = *(const float4*)(in + i + 4);
    short8 o;
    o[0] = (short)f2bf(a.x); o[1] = (short)f2bf(a.y);
    o[2] = (short)f2bf(a.z); o[3] = (short)f2bf(a.w);
    o[4] = (short)f2bf(b.x); o[5] = (short)f2bf(b.y);
    o[6] = (short)f2bf(b.z); o[7] = (short)f2bf(b.w);
    *(short8*)(out + i) = o;
}

// ---------------------------------------------------------------------------
// Transpose fp32 matrix -> bf16: out[C][R] = bf16(in[R][C]).
// ---------------------------------------------------------------------------
__global__ __launch_bounds__(256) void transpose_f32bf_k(
    const float* __restrict__ in, ushort_t* __restrict__ out, int R, int C)
{
    __shared__ float tile[32][33];
    const int tx = threadIdx.x & 31, ty = threadIdx.x >> 5;  // 32 x 8
    const int c0 = blockIdx.x * 32, r0 = blockIdx.y * 32;
#pragma unroll
    for (int i = 0; i < 32; i += 8)
        tile[ty + i][tx] = in[(long)(r0 + ty + i) * C + c0 + tx];
    __syncthreads();
#pragma unroll
    for (int i = 0; i < 32; i += 8)
        out[(long)(c0 + ty + i) * R + r0 + tx] = f2bf(tile[tx][ty + i]);
}

// ---------------------------------------------------------------------------
// Transpose bf16 -> bf16 (for V^T).
// ---------------------------------------------------------------------------
__global__ __launch_bounds__(256) void transpose_bf16_k(
    const ushort_t* __restrict__ in, ushort_t* __restrict__ out, int R, int C)
{
    __shared__ ushort_t tile[32][33];
    const int tx = threadIdx.x & 31, ty = threadIdx.x >> 5;
    const int c0 = blockIdx.x * 32, r0 = blockIdx.y * 32;
#pragma unroll
    for (int i = 0; i < 32; i += 8)
        tile[ty + i][tx] = in[(long)(r0 + ty + i) * C + c0 + tx];
    __syncthreads();
#pragma unroll
    for (int i = 0; i < 32; i += 8)
        out[(long)(c0 + ty + i) * R + r0 + tx] = tile[tx][ty + i];
}

// ---------------------------------------------------------------------------
// imp[b*s] = gelu(x @ Ws1 + bs1) @ Ws2 + bs2   (all fp32, matches reference)
// 512 blocks x 256 threads, 16 tokens/block, thread j = hidden unit j.
// ---------------------------------------------------------------------------
__global__ __launch_bounds__(256) void imp_k(
    const float* __restrict__ x, const float* __restrict__ Ws1,
    const float* __restrict__ bs1, const float* __restrict__ Ws2,
    const float* __restrict__ bs2, float* __restrict__ imp)
{
    __shared__ float xs[16][512];
    __shared__ float red[4][16];
    const int tid = threadIdx.x;
    const int lane = tid & 63, w = tid >> 6;
    const long base = (long)blockIdx.x * (16 * 512);
#pragma unroll
    for (int it = 0; it < 8; ++it) {
        const int e = it * 1024 + tid * 4;  // float index within block tile
        const float4 v = *(const float4*)(x + base + e);
        const int row = e >> 9, col = e & 511;
        *(float4*)&xs[row][col] = v;
    }
    __syncthreads();
    const int j = tid;  // hidden unit 0..255
    float h[16];
    const float b1 = bs1[j];
#pragma unroll
    for (int t = 0; t < 16; ++t) h[t] = b1;
    for (int d = 0; d < 512; d += 4) {
        const float wv0 = Ws1[(d + 0) * 256 + j];
        const float wv1 = Ws1[(d + 1) * 256 + j];
        const float wv2 = Ws1[(d + 2) * 256 + j];
        const float wv3 = Ws1[(d + 3) * 256 + j];
#pragma unroll
        for (int t = 0; t < 16; ++t) {
            const float4 xv = *(const float4*)&xs[t][d];
            h[t] += xv.x * wv0 + xv.y * wv1 + xv.z * wv2 + xv.w * wv3;
        }
    }
    const float w2 = Ws2[j];
#pragma unroll
    for (int t = 0; t < 16; ++t) {
        const float hv = h[t];
        float v = 0.5f * hv * (1.0f + erff(hv * 0.70710678118f)) * w2;  // exact gelu
        v += __shfl_xor(v, 1);  v += __shfl_xor(v, 2);  v += __shfl_xor(v, 4);
        v += __shfl_xor(v, 8);  v += __shfl_xor(v, 16); v += __shfl_xor(v, 32);
        if (lane == 0) red[w][t] = v;
    }
    __syncthreads();
    if (tid < 16)
        imp[blockIdx.x * 16 + tid] =
            red[0][tid] + red[1][tid] + red[2][tid] + red[3][tid] + bs2[0];
}

// ---------------------------------------------------------------------------
// Per-batch exact top-k: bitonic sort (value desc, index asc) of 4096 pairs.
// 2 blocks x 1024 threads. Matches jax.lax.top_k tie semantics (set only).
// ---------------------------------------------------------------------------
__global__ __launch_bounds__(1024) void topk_k(
    const float* __restrict__ imp, int* __restrict__ topidx)
{
    __shared__ float sv[4096];
    __shared__ int   si[4096];
    const int b = blockIdx.x, tid = threadIdx.x;
    for (int i = tid; i < 4096; i += 1024) { sv[i] = imp[b * 4096 + i]; si[i] = i; }
    __syncthreads();
    for (int k = 2; k <= 4096; k <<= 1) {
        for (int j = k >> 1; j > 0; j >>= 1) {
            for (int i = tid; i < 4096; i += 1024) {
                const int ix = i ^ j;
                if (ix > i) {
                    const bool dir = ((i & k) == 0);
                    const float va = sv[i], vb = sv[ix];
                    const int   ia = si[i], ib = si[ix];
                    const bool a_after = (va < vb) || (va == vb && ia > ib);
                    if (a_after == dir) { sv[i] = vb; sv[ix] = va; si[i] = ib; si[ix] = ia; }
                }
            }
            __syncthreads();
        }
    }
    if (tid < TOPK_) topidx[b * TOPK_ + tid] = si[tid];
}

// ---------------------------------------------------------------------------
// Union mask -> compacted ascending column list + gather rowmap. 1 wave.
// ---------------------------------------------------------------------------
__global__ void compact_k(const int* __restrict__ topidx,
                          int* __restrict__ rowmap, int* __restrict__ keffp)
{
    __shared__ unsigned char mask[4096];
    const int lane = threadIdx.x;  // 64 threads = 1 wave
    for (int i = lane; i < 4096; i += 64) mask[i] = 0;
    __syncthreads();
    for (int i = lane; i < B_ * TOPK_; i += 64) mask[topidx[i]] = 1;
    __syncthreads();
    int base = 0;
    for (int c = 0; c < 64; ++c) {
        const int pos = c * 64 + lane;
        const bool f = mask[pos] != 0;
        const unsigned long long bal = __ballot(f);
        const int rank = __popcll(bal & ((1ull << lane) - 1ull));
        if (f) {
            const int s = base + rank;
            rowmap[s] = pos;                  // batch 0 token row
            rowmap[KSLOTS_ + s] = 4096 + pos; // batch 1 token row
        }
        base += __popcll(bal);
    }
    for (int s = base + lane; s < KSLOTS_; s += 64) {
        rowmap[s] = 0; rowmap[KSLOTS_ + s] = 4096;  // pad -> token 0 (masked)
    }
    if (lane == 0) keffp[0] = base;
}

// ---------------------------------------------------------------------------
// GEMM: C[M][512] = A[M][512] @ W + bias, W given as WT (=W^T), bf16 MFMA.
// Block 256 thr = 4 waves; tile 128x64. Optional row gather (K/V projection).
// Output: fp32 (Cf) if non-null else bf16 (Cb).
// ---------------------------------------------------------------------------
__global__ __launch_bounds__(256) void gemm_k(
    const ushort_t* __restrict__ A, const ushort_t* __restrict__ WT,
    const float* __restrict__ bias, ushort_t* __restrict__ Cb,
    float* __restrict__ Cf, const int* __restrict__ row_map)
{
    const int K = 512, N = 512;
    const int tid = threadIdx.x, lane = tid & 63, w = tid >> 6;
    const int l15 = lane & 15, l4 = lane >> 4;
    const int m_base = blockIdx.x * 128 + w * 32;
    const int n_base = blockIdx.y * 64;

    const int r0 = m_base + l15;
    const int r1 = m_base + 16 + l15;
    const long ar0 = row_map ? (long)row_map[r0] : (long)r0;
    const long ar1 = row_map ? (long)row_map[r1] : (long)r1;
    const ushort_t* a0p = A + ar0 * K + l4 * 8;
    const ushort_t* a1p = A + ar1 * K + l4 * 8;
    const ushort_t* bp0 = WT + (long)(n_base +  0 + l15) * K + l4 * 8;
    const ushort_t* bp1 = WT + (long)(n_base + 16 + l15) * K + l4 * 8;
    const ushort_t* bp2 = WT + (long)(n_base + 32 + l15) * K + l4 * 8;
    const ushort_t* bp3 = WT + (long)(n_base + 48 + l15) * K + l4 * 8;

    f32x4 acc[2][4] = {};
#pragma unroll 4
    for (int kk = 0; kk < 16; ++kk) {
        const int ko = kk * 32;
        const short8 a0 = *(const short8*)(a0p + ko);
        const short8 a1 = *(const short8*)(a1p + ko);
        const short8 b0 = *(const short8*)(bp0 + ko);
        const short8 b1 = *(const short8*)(bp1 + ko);
        const short8 b2 = *(const short8*)(bp2 + ko);
        const short8 b3 = *(const short8*)(bp3 + ko);
        acc[0][0] = __builtin_amdgcn_mfma_f32_16x16x32_bf16(a0, b0, acc[0][0], 0, 0, 0);
        acc[1][0] = __builtin_amdgcn_mfma_f32_16x16x32_bf16(a1, b0, acc[1][0], 0, 0, 0);
        acc[0][1] = __builtin_amdgcn_mfma_f32_16x16x32_bf16(a0, b1, acc[0][1], 0, 0, 0);
        acc[1][1] = __builtin_amdgcn_mfma_f32_16x16x32_bf16(a1, b1, acc[1][1], 0, 0, 0);
        acc[0][2] = __builtin_amdgcn_mfma_f32_16x16x32_bf16(a0, b2, acc[0][2], 0, 0, 0);
        acc[1][2] = __builtin_amdgcn_mfma_f32_16x16x32_bf16(a1, b2, acc[1][2], 0, 0, 0);
        acc[0][3] = __builtin_amdgcn_mfma_f32_16x16x32_bf16(a0, b3, acc[0][3], 0, 0, 0);
        acc[1][3] = __builtin_amdgcn_mfma_f32_16x16x32_bf16(a1, b3, acc[1][3], 0, 0, 0);
    }
#pragma unroll
    for (int g = 0; g < 2; ++g)
#pragma unroll
        for (int c = 0; c < 4; ++c) {
            const int col = n_base + c * 16 + l15;
            const float bv = bias[col];
#pragma unroll
            for (int r = 0; r < 4; ++r) {
                const int row = m_base + g * 16 + l4 * 4 + r;
                const float val = acc[g][c][r] + bv;
                if (Cf) Cf[(long)row * N + col] = val;
                else    Cb[(long)row * N + col] = f2bf(val);
            }
        }
}

// ---------------------------------------------------------------------------
// Flash attention over KSLOTS_ selected keys.
// Grid = B*H*(S/128) = 512 blocks; 4 waves; wave owns 32 q-rows.
// ---------------------------------------------------------------------------
__global__ __launch_bounds__(256) void attn_k(
    const ushort_t* __restrict__ q_all, const ushort_t* __restrict__ k_sel,
    const ushort_t* __restrict__ vT, const int* __restrict__ keff_p,
    ushort_t* __restrict__ att)
{
    __shared__ __align__(16) ushort_t Ps[4][32 * 64];
    const int tid = threadIdx.x;
    const int lane = tid & 63, w = tid >> 6;
    const int l15 = lane & 15, l4 = lane >> 4;
    const int bidx = blockIdx.x;
    const int qt = bidx & 31, h = (bidx >> 5) & 7, b = bidx >> 8;
    const int q0 = qt * 128;
    const int keff = keff_p[0];
    ushort_t* ps = Ps[w];

    short8 qf[2][2];
#pragma unroll
    for (int g = 0; g < 2; ++g) {
        const ushort_t* qrow =
            q_all + (long)(b * 4096 + q0 + w * 32 + g * 16 + l15) * 512 + h * 64;
#pragma unroll
        for (int ks = 0; ks < 2; ++ks)
            qf[g][ks] = *(const short8*)(qrow + ks * 32 + l4 * 8);
    }

    f32x4 acc[2][4] = {};
    float mrun[2][4], lrun[2][4];
#pragma unroll
    for (int g = 0; g < 2; ++g)
#pragma unroll
        for (int r = 0; r < 4; ++r) { mrun[g][r] = -3.0e38f; lrun[g][r] = 0.0f; }

#pragma unroll 1
    for (int t = 0; t < KSLOTS_ / 64; ++t) {
        // ---- scores: Q @ K^T for 64 keys ----
        f32x4 s[2][4] = {};
#pragma unroll
        for (int c = 0; c < 4; ++c) {
            const ushort_t* krow =
                k_sel + (long)(b * KSLOTS_ + t * 64 + c * 16 + l15) * 512 + h * 64;
#pragma unroll
            for (int ks = 0; ks < 2; ++ks) {
                const short8 kf = *(const short8*)(krow + ks * 32 + l4 * 8);
                s[0][c] = __builtin_amdgcn_mfma_f32_16x16x32_bf16(qf[0][ks], kf, s[0][c], 0, 0, 0);
                s[1][c] = __builtin_amdgcn_mfma_f32_16x16x32_bf16(qf[1][ks], kf, s[1][c], 0, 0, 0);
            }
        }
        // ---- scale + pad-mask + online softmax ----
#pragma unroll
        for (int g = 0; g < 2; ++g) {
#pragma unroll
            for (int c = 0; c < 4; ++c) {
                const int col = t * 64 + c * 16 + l15;
                const bool valid = col < keff;
#pragma unroll
                for (int r = 0; r < 4; ++r) {
                    const float v = s[g][c][r] * 0.125f;  // HD^-0.5
                    s[g][c][r] = valid ? v : -1.0e30f;
                }
            }
            float sc[4];
#pragma unroll
            for (int r = 0; r < 4; ++r) {
                float rm = fmaxf(fmaxf(s[g][0][r], s[g][1][r]), fmaxf(s[g][2][r], s[g][3][r]));
                rm = fmaxf(rm, __shfl_xor(rm, 1));
                rm = fmaxf(rm, __shfl_xor(rm, 2));
                rm = fmaxf(rm, __shfl_xor(rm, 4));
                rm = fmaxf(rm, __shfl_xor(rm, 8));
                const float mn = fmaxf(mrun[g][r], rm);
                sc[r] = __expf(mrun[g][r] - mn);
                mrun[g][r] = mn;
            }
#pragma unroll
            for (int c = 0; c < 4; ++c)
#pragma unroll
                for (int r = 0; r < 4; ++r)
                    s[g][c][r] = __expf(s[g][c][r] - mrun[g][r]);
#pragma unroll
            for (int r = 0; r < 4; ++r) {
                float rs = s[g][0][r] + s[g][1][r] + s[g][2][r] + s[g][3][r];
                rs += __shfl_xor(rs, 1);
                rs += __shfl_xor(rs, 2);
                rs += __shfl_xor(rs, 4);
                rs += __shfl_xor(rs, 8);
                lrun[g][r] = lrun[g][r] * sc[r] + rs;
#pragma unroll
                for (int cd = 0; cd < 4; ++cd) acc[g][cd][r] *= sc[r];
            }
            // write P (bf16) to per-wave LDS, XOR-swizzled (G4)
#pragma unroll
            for (int c = 0; c < 4; ++c)
#pragma unroll
                for (int r = 0; r < 4; ++r) {
                    const int ql = g * 16 + l4 * 4 + r;
                    const int kl = c * 16 + l15;
                    ps[ql * 64 + (kl ^ ((ql & 7) << 3))] = f2bf(s[g][c][r]);
                }
        }
        // ---- PV: O += P @ V ----
#pragma unroll
        for (int cd = 0; cd < 4; ++cd) {
            const ushort_t* vrow =
                vT + (long)(b * KSLOTS_ + h * 64 + cd * 16 + l15) * KSLOTS_ + t * 64;
#pragma unroll
            for (int ks = 0; ks < 2; ++ks) {
                const short8 vf = *(const short8*)(vrow + ks * 32 + l4 * 8);
#pragma unroll
                for (int g = 0; g < 2; ++g) {
                    const int ql = g * 16 + l15;
                    const short8 pf = *(const short8*)(
                        ps + ql * 64 + ((l4 * 8 + ks * 32) ^ ((ql & 7) << 3)));
                    acc[g][cd] = __builtin_amdgcn_mfma_f32_16x16x32_bf16(pf, vf, acc[g][cd], 0, 0, 0);
                }
            }
        }
    }
    // ---- normalize + store (b, q, h*64+d), bf16 ----
#pragma unroll
    for (int g = 0; g < 2; ++g)
#pragma unroll
        for (int cd = 0; cd < 4; ++cd)
#pragma unroll
            for (int r = 0; r < 4; ++r) {
                const int row = q0 + w * 32 + g * 16 + l4 * 4 + r;
                att[(long)(b * 4096 + row) * 512 + h * 64 + cd * 16 + l15] =
                    f2bf(acc[g][cd][r] / lrun[g][r]);
            }
}

// ---------------------------------------------------------------------------
extern "C" void kernel_launch(void* const* d_in, const int* in_sizes, int n_in,
                              void* d_out, int out_size, void* d_ws, size_t ws_size,
                              hipStream_t stream)
{
    const float* x   = (const float*)d_in[0];
    const float* Wq  = (const float*)d_in[1];
    const float* bq  = (const float*)d_in[2];
    const float* Wk  = (const float*)d_in[3];
    const float* bk  = (const float*)d_in[4];
    const float* Wv  = (const float*)d_in[5];
    const float* bv  = (const float*)d_in[6];
    const float* Wo  = (const float*)d_in[7];
    const float* bo  = (const float*)d_in[8];
    const float* Ws1 = (const float*)d_in[9];
    const float* bs1 = (const float*)d_in[10];
    const float* Ws2 = (const float*)d_in[11];
    const float* bs2 = (const float*)d_in[12];
    // d_in[13] = top_k (=256; structure hardcoded around it)

    char* ws = (char*)d_ws;
    float*     imp    = (float*)(ws + 0);              // 32 KB
    int*       topidx = (int*)(ws + 0x8000);           // 2 KB
    int*       keffp  = (int*)(ws + 0x8800);
    int*       rowmap = (int*)(ws + 0x9000);           // 4 KB
    ushort_t*  WqT    = (ushort_t*)(ws + 0x10000);     // 4 x 512 KB
    ushort_t*  WkT    = WqT + 512 * 512;
    ushort_t*  WvT    = WkT + 512 * 512;
    ushort_t*  WoT    = WvT + 512 * 512;
    ushort_t*  k_sel  = (ushort_t*)(ws + 0x210000);    // 1 MB
    ushort_t*  v_sel  = (ushort_t*)(ws + 0x310000);    // 1 MB
    ushort_t*  vT     = (ushort_t*)(ws + 0x410000);    // 1 MB
    ushort_t*  xb     = (ushort_t*)(ws + 0x600000);    // 8 MB (reused as att)
    ushort_t*  att    = xb;                            // dead after projections
    ushort_t*  q_all  = (ushort_t*)(ws + 0xE00000);    // 8 MB  (total ~22 MB)

    const dim3 tblk(256);
    // 1. pack x -> bf16
    pack_bf16_k<<<2048, tblk, 0, stream>>>(x, xb);
    // 2. weight transposes (fp32 -> bf16)
    transpose_f32bf_k<<<dim3(16, 16), tblk, 0, stream>>>(Wq, WqT, 512, 512);
    transpose_f32bf_k<<<dim3(16, 16), tblk, 0, stream>>>(Wk, WkT, 512, 512);
    transpose_f32bf_k<<<dim3(16, 16), tblk, 0, stream>>>(Wv, WvT, 512, 512);
    transpose_f32bf_k<<<dim3(16, 16), tblk, 0, stream>>>(Wo, WoT, 512, 512);
    // 3. importance scores (fp32 exact)
    imp_k<<<512, tblk, 0, stream>>>(x, Ws1, bs1, Ws2, bs2, imp);
    // 4. per-batch top-k
    topk_k<<<2, 1024, 0, stream>>>(imp, topidx);
    // 5. union mask -> compacted column list + gather map
    compact_k<<<1, 64, 0, stream>>>(topidx, rowmap, keffp);
    // 6. projections: dense Q, gathered K/V (selected tokens only)
    gemm_k<<<dim3(64, 8), tblk, 0, stream>>>(xb, WqT, bq, q_all, nullptr, nullptr);
    gemm_k<<<dim3(8, 8),  tblk, 0, stream>>>(xb, WkT, bk, k_sel, nullptr, rowmap);
    gemm_k<<<dim3(8, 8),  tblk, 0, stream>>>(xb, WvT, bv, v_sel, nullptr, rowmap);
    // 7. V^T per batch for PV fragment loads
    transpose_bf16_k<<<dim3(16, 16), tblk, 0, stream>>>(v_sel, vT, 512, 512);
    transpose_bf16_k<<<dim3(16, 16), tblk, 0, stream>>>(v_sel + 512 * 512, vT + 512 * 512, 512, 512);
    // 8. sparse flash attention (att overwrites xb region — xb is dead now)
    attn_k<<<512, tblk, 0, stream>>>(q_all, k_sel, vT, keffp, att);
    // 9. output projection -> d_out (fp32)
    gemm_k<<<dim3(64, 8), tblk, 0, stream>>>(att, WoT, bo, nullptr, (float*)d_out, nullptr);
}

// Round 3
// 224.700 us; speedup vs baseline: 1.2620x; 1.2620x over previous
//
#include <hip/hip_runtime.h>
#include <hip/hip_bf16.h>

typedef unsigned short ushort_t;
typedef short short8 __attribute__((ext_vector_type(8)));
typedef float f32x4 __attribute__((ext_vector_type(4)));

#define B_  2
#define S_  4096
#define D_  512
#define H_  8
#define HD_ 64
#define DK_ 256
#define TOPK_ 256
#define KSLOTS_ 512   // 2*TOPK_ slots (union of both batches' top-k)

__device__ __forceinline__ float bf2f(ushort_t u) {
    unsigned int b = ((unsigned int)u) << 16;
    float f;
    __builtin_memcpy(&f, &b, 4);
    return f;
}
__device__ __forceinline__ ushort_t f2bf(float f) {
    unsigned int b;
    __builtin_memcpy(&b, &f, 4);
    b = (b + 0x7FFFu + ((b >> 16) & 1u)) >> 16;
    return (ushort_t)b;
}

// ---------------------------------------------------------------------------
// fp32 -> bf16 pack, 8 elements/thread. total = 8192*512 elements.
// ---------------------------------------------------------------------------
__global__ __launch_bounds__(256) void pack_bf16_k(
    const float* __restrict__ in, ushort_t* __restrict__ out)
{
    const long i = ((long)blockIdx.x * 256 + threadIdx.x) * 8;
    const float4 a = *(const float4*)(in + i);
    const float4 b = *(const float4*)(in + i + 4);
    short8 o;
    o[0] = (short)f2bf(a.x); o[1] = (short)f2bf(a.y);
    o[2] = (short)f2bf(a.z); o[3] = (short)f2bf(a.w);
    o[4] = (short)f2bf(b.x); o[5] = (short)f2bf(b.y);
    o[6] = (short)f2bf(b.z); o[7] = (short)f2bf(b.w);
    *(short8*)(out + i) = o;
}

// ---------------------------------------------------------------------------
// Transpose fp32 matrix -> bf16: out[C][R] = bf16(in[R][C]).
// ---------------------------------------------------------------------------
__global__ __launch_bounds__(256) void transpose_f32bf_k(
    const float* __restrict__ in, ushort_t* __restrict__ out, int R, int C)
{
    __shared__ float tile[32][33];
    const int tx = threadIdx.x & 31, ty = threadIdx.x >> 5;  // 32 x 8
    const int c0 = blockIdx.x * 32, r0 = blockIdx.y * 32;
#pragma unroll
    for (int i = 0; i < 32; i += 8)
        tile[ty + i][tx] = in[(long)(r0 + ty + i) * C + c0 + tx];
    __syncthreads();
#pragma unroll
    for (int i = 0; i < 32; i += 8)
        out[(long)(c0 + ty + i) * R + r0 + tx] = f2bf(tile[tx][ty + i]);
}

// ---------------------------------------------------------------------------
// Transpose bf16 -> bf16 (for V^T).
// ---------------------------------------------------------------------------
__global__ __launch_bounds__(256) void transpose_bf16_k(
    const ushort_t* __restrict__ in, ushort_t* __restrict__ out, int R, int C)
{
    __shared__ ushort_t tile[32][33];
    const int tx = threadIdx.x & 31, ty = threadIdx.x >> 5;
    const int c0 = blockIdx.x * 32, r0 = blockIdx.y * 32;
#pragma unroll
    for (int i = 0; i < 32; i += 8)
        tile[ty + i][tx] = in[(long)(r0 + ty + i) * C + c0 + tx];
    __syncthreads();
#pragma unroll
    for (int i = 0; i < 32; i += 8)
        out[(long)(c0 + ty + i) * R + r0 + tx] = tile[tx][ty + i];
}

// ---------------------------------------------------------------------------
// imp[b*s] = gelu(x @ Ws1 + bs1) @ Ws2 + bs2   (all fp32, matches reference)
// v2: 1024 blocks x 256 threads, 8 tokens/block (4 blocks/CU -> 50% occ cap),
// register weight chunk + next-chunk prefetch, d unrolled x8.
// ---------------------------------------------------------------------------
__global__ __launch_bounds__(256, 4) void imp_k(
    const float* __restrict__ x, const float* __restrict__ Ws1,
    const float* __restrict__ bs1, const float* __restrict__ Ws2,
    const float* __restrict__ bs2, float* __restrict__ imp)
{
    __shared__ float xs[8][512];
    __shared__ float red[4][8];
    const int tid = threadIdx.x;
    const int lane = tid & 63, w = tid >> 6;
    const long base = (long)blockIdx.x * (8 * 512);
#pragma unroll
    for (int it = 0; it < 4; ++it) {
        const int e = it * 1024 + tid * 4;
        const float4 v = *(const float4*)(x + base + e);
        *(float4*)&xs[e >> 9][e & 511] = v;
    }
    __syncthreads();
    const int j = tid;  // hidden unit 0..255
    float h[8];
    const float b1 = bs1[j];
#pragma unroll
    for (int t = 0; t < 8; ++t) h[t] = b1;
    float wreg[8];
#pragma unroll
    for (int q = 0; q < 8; ++q) wreg[q] = Ws1[q * 256 + j];
#pragma unroll 2
    for (int d = 0; d < 512; d += 8) {
        const int dn = (d + 8) & 511;  // wraps to 0 on last iter (discarded)
        float wnext[8];
#pragma unroll
        for (int q = 0; q < 8; ++q) wnext[q] = Ws1[(dn + q) * 256 + j];
#pragma unroll
        for (int t = 0; t < 8; ++t) {
            const float4 x0 = *(const float4*)&xs[t][d];
            const float4 x1 = *(const float4*)&xs[t][d + 4];
            h[t] += x0.x * wreg[0] + x0.y * wreg[1] + x0.z * wreg[2] + x0.w * wreg[3]
                  + x1.x * wreg[4] + x1.y * wreg[5] + x1.z * wreg[6] + x1.w * wreg[7];
        }
#pragma unroll
        for (int q = 0; q < 8; ++q) wreg[q] = wnext[q];
    }
    const float w2 = Ws2[j];
#pragma unroll
    for (int t = 0; t < 8; ++t) {
        const float hv = h[t];
        float v = 0.5f * hv * (1.0f + erff(hv * 0.70710678118f)) * w2;  // exact gelu
        v += __shfl_xor(v, 1);  v += __shfl_xor(v, 2);  v += __shfl_xor(v, 4);
        v += __shfl_xor(v, 8);  v += __shfl_xor(v, 16); v += __shfl_xor(v, 32);
        if (lane == 0) red[w][t] = v;
    }
    __syncthreads();
    if (tid < 8)
        imp[blockIdx.x * 8 + tid] =
            red[0][tid] + red[1][tid] + red[2][tid] + red[3][tid] + bs2[0];
}

// ---------------------------------------------------------------------------
// Per-batch exact top-k via radix-select (byte histogram descent), then
// index-ordered tie resolution. Matches jax.lax.top_k selected SET:
// all values > T, plus the first (k - count_gt) indices with value == T.
// One block (1024 thr) per batch. Writes sel[b][i] in {0,1}.
// ---------------------------------------------------------------------------
__global__ __launch_bounds__(1024) void topk_select_k(
    const float* __restrict__ imp, unsigned char* __restrict__ sel)
{
    __shared__ unsigned int keys[4096];
    __shared__ unsigned int hist[256];
    __shared__ int chunkscan[64];
    __shared__ unsigned int sh_prefix;
    __shared__ int sh_rem;
    const int b = blockIdx.x, tid = threadIdx.x;
    const int lane = tid & 63, w = tid >> 6;
    for (int i = tid; i < 4096; i += 1024) {
        const unsigned int u = __float_as_uint(imp[b * 4096 + i]);
        keys[i] = (u & 0x80000000u) ? ~u : (u | 0x80000000u);  // order-preserving
    }
    if (tid == 0) { sh_prefix = 0u; sh_rem = TOPK_; }
    __syncthreads();
    unsigned int pmask = 0;
    for (int level = 3; level >= 0; --level) {
        const int shb = level * 8;
        const unsigned int prefix = sh_prefix;
        const int remaining = sh_rem;
        if (tid < 256) hist[tid] = 0;
        __syncthreads();
        for (int i = tid; i < 4096; i += 1024) {
            const unsigned int u = keys[i];
            if ((u & pmask) == prefix) atomicAdd(&hist[(u >> shb) & 255u], 1u);
        }
        __syncthreads();
        if (tid < 64) {
            // descending order: position p -> bin (255-p); lane owns p = tid*4..+3
            unsigned int v[4];
            int tot = 0;
#pragma unroll
            for (int q = 0; q < 4; ++q) { v[q] = hist[255 - (tid * 4 + q)]; tot += (int)v[q]; }
            int pre = tot;
            for (int off = 1; off < 64; off <<= 1) {
                const int t = __shfl_up(pre, off);
                if (tid >= off) pre += t;
            }
            const unsigned long long bal = __ballot(pre >= remaining);
            const int L = __ffsll((unsigned long long)bal) - 1;
            if (tid == L) {
                int c = pre - tot;
#pragma unroll
                for (int q = 0; q < 4; ++q) {
                    c += (int)v[q];
                    if (c >= remaining) {
                        sh_rem = remaining - (c - (int)v[q]);
                        sh_prefix = prefix | ((unsigned int)(255 - (tid * 4 + q)) << shb);
                        break;
                    }
                }
            }
        }
        __syncthreads();
        pmask |= (255u << shb);
    }
    const unsigned int T = sh_prefix;
    const int need = sh_rem;  // how many of the == T elements to take (index asc)
    // per-64-chunk counts of (key == T), in index order
#pragma unroll
    for (int q = 0; q < 4; ++q) {
        const int chunk = w * 4 + q;
        const unsigned long long bal = __ballot(keys[chunk * 64 + lane] == T);
        if (lane == 0) chunkscan[chunk] = __popcll(bal);
    }
    __syncthreads();
    if (tid < 64) {
        const int v = chunkscan[tid];
        int pre = v;
        for (int off = 1; off < 64; off <<= 1) {
            const int t = __shfl_up(pre, off);
            if (tid >= off) pre += t;
        }
        chunkscan[tid] = pre - v;  // exclusive prefix (wave-lockstep safe)
    }
    __syncthreads();
#pragma unroll
    for (int q = 0; q < 4; ++q) {
        const int chunk = w * 4 + q;
        const int i = chunk * 64 + lane;
        const unsigned int u = keys[i];
        const bool eq = (u == T);
        const unsigned long long bal = __ballot(eq);
        const int rank = chunkscan[chunk] + __popcll(bal & ((1ull << lane) - 1ull));
        sel[b * 4096 + i] = (u > T || (eq && rank < need)) ? 1 : 0;
    }
}

// ---------------------------------------------------------------------------
// Union of per-batch selections -> compacted ascending column list + gather
// rowmap. 1 wave.
// ---------------------------------------------------------------------------
__global__ void compact_k(const unsigned char* __restrict__ sel,
                          int* __restrict__ rowmap, int* __restrict__ keffp)
{
    const int lane = threadIdx.x;  // 64 threads = 1 wave
    int base = 0;
    for (int c = 0; c < 64; ++c) {
        const int pos = c * 64 + lane;
        const bool f = (sel[pos] | sel[4096 + pos]) != 0;
        const unsigned long long bal = __ballot(f);
        const int rank = __popcll(bal & ((1ull << lane) - 1ull));
        if (f) {
            const int s = base + rank;
            rowmap[s] = pos;                  // batch 0 token row
            rowmap[KSLOTS_ + s] = 4096 + pos; // batch 1 token row
        }
        base += __popcll(bal);
    }
    for (int s = base + lane; s < KSLOTS_; s += 64) {
        rowmap[s] = 0; rowmap[KSLOTS_ + s] = 4096;  // pad -> token 0 (masked)
    }
    if (lane == 0) keffp[0] = base;
}

// ---------------------------------------------------------------------------
// GEMM: C[M][512] = A[M][512] @ W + bias, W given as WT (=W^T), bf16 MFMA.
// Block 256 thr = 4 waves; tile 128x64. Optional row gather (K/V projection).
// Output: fp32 (Cf) if non-null else bf16 (Cb).
// ---------------------------------------------------------------------------
__global__ __launch_bounds__(256) void gemm_k(
    const ushort_t* __restrict__ A, const ushort_t* __restrict__ WT,
    const float* __restrict__ bias, ushort_t* __restrict__ Cb,
    float* __restrict__ Cf, const int* __restrict__ row_map)
{
    const int K = 512, N = 512;
    const int tid = threadIdx.x, lane = tid & 63, w = tid >> 6;
    const int l15 = lane & 15, l4 = lane >> 4;
    const int m_base = blockIdx.x * 128 + w * 32;
    const int n_base = blockIdx.y * 64;

    const int r0 = m_base + l15;
    const int r1 = m_base + 16 + l15;
    const long ar0 = row_map ? (long)row_map[r0] : (long)r0;
    const long ar1 = row_map ? (long)row_map[r1] : (long)r1;
    const ushort_t* a0p = A + ar0 * K + l4 * 8;
    const ushort_t* a1p = A + ar1 * K + l4 * 8;
    const ushort_t* bp0 = WT + (long)(n_base +  0 + l15) * K + l4 * 8;
    const ushort_t* bp1 = WT + (long)(n_base + 16 + l15) * K + l4 * 8;
    const ushort_t* bp2 = WT + (long)(n_base + 32 + l15) * K + l4 * 8;
    const ushort_t* bp3 = WT + (long)(n_base + 48 + l15) * K + l4 * 8;

    f32x4 acc[2][4] = {};
#pragma unroll 4
    for (int kk = 0; kk < 16; ++kk) {
        const int ko = kk * 32;
        const short8 a0 = *(const short8*)(a0p + ko);
        const short8 a1 = *(const short8*)(a1p + ko);
        const short8 b0 = *(const short8*)(bp0 + ko);
        const short8 b1 = *(const short8*)(bp1 + ko);
        const short8 b2 = *(const short8*)(bp2 + ko);
        const short8 b3 = *(const short8*)(bp3 + ko);
        acc[0][0] = __builtin_amdgcn_mfma_f32_16x16x32_bf16(a0, b0, acc[0][0], 0, 0, 0);
        acc[1][0] = __builtin_amdgcn_mfma_f32_16x16x32_bf16(a1, b0, acc[1][0], 0, 0, 0);
        acc[0][1] = __builtin_amdgcn_mfma_f32_16x16x32_bf16(a0, b1, acc[0][1], 0, 0, 0);
        acc[1][1] = __builtin_amdgcn_mfma_f32_16x16x32_bf16(a1, b1, acc[1][1], 0, 0, 0);
        acc[0][2] = __builtin_amdgcn_mfma_f32_16x16x32_bf16(a0, b2, acc[0][2], 0, 0, 0);
        acc[1][2] = __builtin_amdgcn_mfma_f32_16x16x32_bf16(a1, b2, acc[1][2], 0, 0, 0);
        acc[0][3] = __builtin_amdgcn_mfma_f32_16x16x32_bf16(a0, b3, acc[0][3], 0, 0, 0);
        acc[1][3] = __builtin_amdgcn_mfma_f32_16x16x32_bf16(a1, b3, acc[1][3], 0, 0, 0);
    }
#pragma unroll
    for (int g = 0; g < 2; ++g)
#pragma unroll
        for (int c = 0; c < 4; ++c) {
            const int col = n_base + c * 16 + l15;
            const float bv = bias[col];
#pragma unroll
            for (int r = 0; r < 4; ++r) {
                const int row = m_base + g * 16 + l4 * 4 + r;
                const float val = acc[g][c][r] + bv;
                if (Cf) Cf[(long)row * N + col] = val;
                else    Cb[(long)row * N + col] = f2bf(val);
            }
        }
}

// ---------------------------------------------------------------------------
// Flash attention over KSLOTS_ selected keys.
// Grid = B*H*(S/128) = 512 blocks; 4 waves; wave owns 32 q-rows.
// ---------------------------------------------------------------------------
__global__ __launch_bounds__(256) void attn_k(
    const ushort_t* __restrict__ q_all, const ushort_t* __restrict__ k_sel,
    const ushort_t* __restrict__ vT, const int* __restrict__ keff_p,
    ushort_t* __restrict__ att)
{
    __shared__ __align__(16) ushort_t Ps[4][32 * 64];
    const int tid = threadIdx.x;
    const int lane = tid & 63, w = tid >> 6;
    const int l15 = lane & 15, l4 = lane >> 4;
    const int bidx = blockIdx.x;
    const int qt = bidx & 31, h = (bidx >> 5) & 7, b = bidx >> 8;
    const int q0 = qt * 128;
    const int keff = keff_p[0];
    ushort_t* ps = Ps[w];

    short8 qf[2][2];
#pragma unroll
    for (int g = 0; g < 2; ++g) {
        const ushort_t* qrow =
            q_all + (long)(b * 4096 + q0 + w * 32 + g * 16 + l15) * 512 + h * 64;
#pragma unroll
        for (int ks = 0; ks < 2; ++ks)
            qf[g][ks] = *(const short8*)(qrow + ks * 32 + l4 * 8);
    }

    f32x4 acc[2][4] = {};
    float mrun[2][4], lrun[2][4];
#pragma unroll
    for (int g = 0; g < 2; ++g)
#pragma unroll
        for (int r = 0; r < 4; ++r) { mrun[g][r] = -3.0e38f; lrun[g][r] = 0.0f; }

#pragma unroll 1
    for (int t = 0; t < KSLOTS_ / 64; ++t) {
        // ---- scores: Q @ K^T for 64 keys ----
        f32x4 s[2][4] = {};
#pragma unroll
        for (int c = 0; c < 4; ++c) {
            const ushort_t* krow =
                k_sel + (long)(b * KSLOTS_ + t * 64 + c * 16 + l15) * 512 + h * 64;
#pragma unroll
            for (int ks = 0; ks < 2; ++ks) {
                const short8 kf = *(const short8*)(krow + ks * 32 + l4 * 8);
                s[0][c] = __builtin_amdgcn_mfma_f32_16x16x32_bf16(qf[0][ks], kf, s[0][c], 0, 0, 0);
                s[1][c] = __builtin_amdgcn_mfma_f32_16x16x32_bf16(qf[1][ks], kf, s[1][c], 0, 0, 0);
            }
        }
        // ---- scale + pad-mask + online softmax ----
#pragma unroll
        for (int g = 0; g < 2; ++g) {
#pragma unroll
            for (int c = 0; c < 4; ++c) {
                const int col = t * 64 + c * 16 + l15;
                const bool valid = col < keff;
#pragma unroll
                for (int r = 0; r < 4; ++r) {
                    const float v = s[g][c][r] * 0.125f;  // HD^-0.5
                    s[g][c][r] = valid ? v : -1.0e30f;
                }
            }
            float sc[4];
#pragma unroll
            for (int r = 0; r < 4; ++r) {
                float rm = fmaxf(fmaxf(s[g][0][r], s[g][1][r]), fmaxf(s[g][2][r], s[g][3][r]));
                rm = fmaxf(rm, __shfl_xor(rm, 1));
                rm = fmaxf(rm, __shfl_xor(rm, 2));
                rm = fmaxf(rm, __shfl_xor(rm, 4));
                rm = fmaxf(rm, __shfl_xor(rm, 8));
                const float mn = fmaxf(mrun[g][r], rm);
                sc[r] = __expf(mrun[g][r] - mn);
                mrun[g][r] = mn;
            }
#pragma unroll
            for (int c = 0; c < 4; ++c)
#pragma unroll
                for (int r = 0; r < 4; ++r)
                    s[g][c][r] = __expf(s[g][c][r] - mrun[g][r]);
#pragma unroll
            for (int r = 0; r < 4; ++r) {
                float rs = s[g][0][r] + s[g][1][r] + s[g][2][r] + s[g][3][r];
                rs += __shfl_xor(rs, 1);
                rs += __shfl_xor(rs, 2);
                rs += __shfl_xor(rs, 4);
                rs += __shfl_xor(rs, 8);
                lrun[g][r] = lrun[g][r] * sc[r] + rs;
#pragma unroll
                for (int cd = 0; cd < 4; ++cd) acc[g][cd][r] *= sc[r];
            }
            // write P (bf16) to per-wave LDS, XOR-swizzled (G4)
#pragma unroll
            for (int c = 0; c < 4; ++c)
#pragma unroll
                for (int r = 0; r < 4; ++r) {
                    const int ql = g * 16 + l4 * 4 + r;
                    const int kl = c * 16 + l15;
                    ps[ql * 64 + (kl ^ ((ql & 7) << 3))] = f2bf(s[g][c][r]);
                }
        }
        // ---- PV: O += P @ V ----
#pragma unroll
        for (int cd = 0; cd < 4; ++cd) {
            const ushort_t* vrow =
                vT + (long)(b * KSLOTS_ + h * 64 + cd * 16 + l15) * KSLOTS_ + t * 64;
#pragma unroll
            for (int ks = 0; ks < 2; ++ks) {
                const short8 vf = *(const short8*)(vrow + ks * 32 + l4 * 8);
#pragma unroll
                for (int g = 0; g < 2; ++g) {
                    const int ql = g * 16 + l15;
                    const short8 pf = *(const short8*)(
                        ps + ql * 64 + ((l4 * 8 + ks * 32) ^ ((ql & 7) << 3)));
                    acc[g][cd] = __builtin_amdgcn_mfma_f32_16x16x32_bf16(pf, vf, acc[g][cd], 0, 0, 0);
                }
            }
        }
    }
    // ---- normalize + store (b, q, h*64+d), bf16 ----
#pragma unroll
    for (int g = 0; g < 2; ++g)
#pragma unroll
        for (int cd = 0; cd < 4; ++cd)
#pragma unroll
            for (int r = 0; r < 4; ++r) {
                const int row = q0 + w * 32 + g * 16 + l4 * 4 + r;
                att[(long)(b * 4096 + row) * 512 + h * 64 + cd * 16 + l15] =
                    f2bf(acc[g][cd][r] / lrun[g][r]);
            }
}

// ---------------------------------------------------------------------------
extern "C" void kernel_launch(void* const* d_in, const int* in_sizes, int n_in,
                              void* d_out, int out_size, void* d_ws, size_t ws_size,
                              hipStream_t stream)
{
    const float* x   = (const float*)d_in[0];
    const float* Wq  = (const float*)d_in[1];
    const float* bq  = (const float*)d_in[2];
    const float* Wk  = (const float*)d_in[3];
    const float* bk  = (const float*)d_in[4];
    const float* Wv  = (const float*)d_in[5];
    const float* bv  = (const float*)d_in[6];
    const float* Wo  = (const float*)d_in[7];
    const float* bo  = (const float*)d_in[8];
    const float* Ws1 = (const float*)d_in[9];
    const float* bs1 = (const float*)d_in[10];
    const float* Ws2 = (const float*)d_in[11];
    const float* bs2 = (const float*)d_in[12];
    // d_in[13] = top_k (=256; structure hardcoded around it)

    char* ws = (char*)d_ws;
    float*          imp    = (float*)(ws + 0);           // 32 KB
    unsigned char*  sel    = (unsigned char*)(ws + 0x8000); // 8 KB
    int*            keffp  = (int*)(ws + 0xA000);
    int*            rowmap = (int*)(ws + 0xA800);        // 4 KB
    ushort_t*  WqT    = (ushort_t*)(ws + 0x10000);       // 4 x 512 KB
    ushort_t*  WkT    = WqT + 512 * 512;
    ushort_t*  WvT    = WkT + 512 * 512;
    ushort_t*  WoT    = WvT + 512 * 512;
    ushort_t*  k_sel  = (ushort_t*)(ws + 0x210000);      // 1 MB
    ushort_t*  v_sel  = (ushort_t*)(ws + 0x310000);      // 1 MB
    ushort_t*  vT     = (ushort_t*)(ws + 0x410000);      // 1 MB
    ushort_t*  xb     = (ushort_t*)(ws + 0x600000);      // 8 MB (reused as att)
    ushort_t*  att    = xb;                              // dead after projections
    ushort_t*  q_all  = (ushort_t*)(ws + 0xE00000);      // 8 MB  (total ~22 MB)

    const dim3 tblk(256);
    // 1. pack x -> bf16
    pack_bf16_k<<<2048, tblk, 0, stream>>>(x, xb);
    // 2. weight transposes (fp32 -> bf16)
    transpose_f32bf_k<<<dim3(16, 16), tblk, 0, stream>>>(Wq, WqT, 512, 512);
    transpose_f32bf_k<<<dim3(16, 16), tblk, 0, stream>>>(Wk, WkT, 512, 512);
    transpose_f32bf_k<<<dim3(16, 16), tblk, 0, stream>>>(Wv, WvT, 512, 512);
    transpose_f32bf_k<<<dim3(16, 16), tblk, 0, stream>>>(Wo, WoT, 512, 512);
    // 3. importance scores (fp32 exact)
    imp_k<<<1024, tblk, 0, stream>>>(x, Ws1, bs1, Ws2, bs2, imp);
    // 4. per-batch top-k via radix select
    topk_select_k<<<2, 1024, 0, stream>>>(imp, sel);
    // 5. union mask -> compacted column list + gather map
    compact_k<<<1, 64, 0, stream>>>(sel, rowmap, keffp);
    // 6. projections: dense Q, gathered K/V (selected tokens only)
    gemm_k<<<dim3(64, 8), tblk, 0, stream>>>(xb, WqT, bq, q_all, nullptr, nullptr);
    gemm_k<<<dim3(8, 8),  tblk, 0, stream>>>(xb, WkT, bk, k_sel, nullptr, rowmap);
    gemm_k<<<dim3(8, 8),  tblk, 0, stream>>>(xb, WvT, bv, v_sel, nullptr, rowmap);
    // 7. V^T per batch for PV fragment loads
    transpose_bf16_k<<<dim3(16, 16), tblk, 0, stream>>>(v_sel, vT, 512, 512);
    transpose_bf16_k<<<dim3(16, 16), tblk, 0, stream>>>(v_sel + 512 * 512, vT + 512 * 512, 512, 512);
    // 8. sparse flash attention (att overwrites xb region — xb is dead now)
    attn_k<<<512, tblk, 0, stream>>>(q_all, k_sel, vT, keffp, att);
    // 9. output projection -> d_out (fp32)
    gemm_k<<<dim3(64, 8), tblk, 0, stream>>>(att, WoT, bo, nullptr, (float*)d_out, nullptr);
}

// Round 4
// 215.343 us; speedup vs baseline: 1.3168x; 1.0435x over previous
//
#include <hip/hip_runtime.h>
#include <hip/hip_bf16.h>

typedef unsigned short ushort_t;
typedef short short8 __attribute__((ext_vector_type(8)));
typedef float f32x4 __attribute__((ext_vector_type(4)));

#define B_  2
#define S_  4096
#define D_  512
#define H_  8
#define HD_ 64
#define DK_ 256
#define TOPK_ 256
#define KSLOTS_ 512   // 2*TOPK_ slots (union of both batches' top-k)

__device__ __forceinline__ float bf2f(ushort_t u) {
    unsigned int b = ((unsigned int)u) << 16;
    float f;
    __builtin_memcpy(&f, &b, 4);
    return f;
}
__device__ __forceinline__ ushort_t f2bf(float f) {
    unsigned int b;
    __builtin_memcpy(&b, &f, 4);
    b = (b + 0x7FFFu + ((b >> 16) & 1u)) >> 16;
    return (ushort_t)b;
}

// ---------------------------------------------------------------------------
// fp32 -> bf16 pack, 8 elements/thread. total = 8192*512 elements.
// ---------------------------------------------------------------------------
__global__ __launch_bounds__(256) void pack_bf16_k(
    const float* __restrict__ in, ushort_t* __restrict__ out)
{
    const long i = ((long)blockIdx.x * 256 + threadIdx.x) * 8;
    const float4 a = *(const float4*)(in + i);
    const float4 b = *(const float4*)(in + i + 4);
    short8 o;
    o[0] = (short)f2bf(a.x); o[1] = (short)f2bf(a.y);
    o[2] = (short)f2bf(a.z); o[3] = (short)f2bf(a.w);
    o[4] = (short)f2bf(b.x); o[5] = (short)f2bf(b.y);
    o[6] = (short)f2bf(b.z); o[7] = (short)f2bf(b.w);
    *(short8*)(out + i) = o;
}

// ---------------------------------------------------------------------------
// Fused transpose of the 4 weight matrices fp32 -> bf16 (blockIdx.z selects).
// out[C][R] = bf16(in[R][C]), 512x512 each.
// ---------------------------------------------------------------------------
__global__ __launch_bounds__(256) void transpose4_f32bf_k(
    const float* __restrict__ W0, const float* __restrict__ W1,
    const float* __restrict__ W2, const float* __restrict__ W3,
    ushort_t* __restrict__ O0, ushort_t* __restrict__ O1,
    ushort_t* __restrict__ O2, ushort_t* __restrict__ O3)
{
    const int z = blockIdx.z;
    const float* in = (z == 0) ? W0 : (z == 1) ? W1 : (z == 2) ? W2 : W3;
    ushort_t*   out = (z == 0) ? O0 : (z == 1) ? O1 : (z == 2) ? O2 : O3;
    __shared__ float tile[32][33];
    const int tx = threadIdx.x & 31, ty = threadIdx.x >> 5;  // 32 x 8
    const int c0 = blockIdx.x * 32, r0 = blockIdx.y * 32;
#pragma unroll
    for (int i = 0; i < 32; i += 8)
        tile[ty + i][tx] = in[(long)(r0 + ty + i) * 512 + c0 + tx];
    __syncthreads();
#pragma unroll
    for (int i = 0; i < 32; i += 8)
        out[(long)(c0 + ty + i) * 512 + r0 + tx] = f2bf(tile[tx][ty + i]);
}

// ---------------------------------------------------------------------------
// imp partials: v3. lane = token (64 tokens/wave, shared x-tile in LDS),
// wave = 16 hidden units (weights via wave-uniform s_load, zero LDS cost).
// Grid = 128 token-groups x 4 hidden-groups = 512 blocks.
// Writes imp_part[hg][token] = sum_{j in hg} gelu(h_j) * Ws2[j]  (fp32 exact).
// ---------------------------------------------------------------------------
__global__ __launch_bounds__(256) void imp_k(
    const float* __restrict__ x, const float* __restrict__ Ws1,
    const float* __restrict__ bs1, const float* __restrict__ Ws2,
    float* __restrict__ imp_part)
{
    __shared__ float xs[2][64][66];   // [dbuf][token][k-chunk+pad]
    __shared__ float red[4][64];
    const int tid = threadIdx.x;
    const int lane = tid & 63, w = tid >> 6;
    const int tg = blockIdx.x >> 2, hg = blockIdx.x & 3;
    const int t0 = tg * 64;
    const int j0 = __builtin_amdgcn_readfirstlane(hg * 64 + w * 16);

    // staging mapping: tk = token 0..63, kq = 16-float quarter of the 64-k chunk
    const int tk = tid >> 2, kq = tid & 3;
    const float* gsrc = x + (long)(t0 + tk) * 512 + kq * 16;

    float4 st[4];
#pragma unroll
    for (int m = 0; m < 4; ++m) st[m] = *(const float4*)(gsrc + m * 4);

    float acc[16];
#pragma unroll
    for (int q = 0; q < 16; ++q) acc[q] = bs1[j0 + q];

    // write chunk 0, prefetch chunk 1
#pragma unroll
    for (int m = 0; m < 4; ++m) *(float4*)&xs[0][tk][kq * 16 + m * 4] = st[m];
#pragma unroll
    for (int m = 0; m < 4; ++m) st[m] = *(const float4*)(gsrc + 64 + m * 4);
    __syncthreads();

#pragma unroll 1
    for (int c = 0; c < 8; ++c) {
        const int buf = c & 1;
        const float* wbase = Ws1 + (c * 64) * 256 + j0;
#pragma unroll 4
        for (int k4 = 0; k4 < 16; ++k4) {
            const float4 xv = *(const float4*)&xs[buf][lane][k4 * 4];
#pragma unroll
            for (int kk = 0; kk < 4; ++kk) {
                const float xk = (kk == 0) ? xv.x : (kk == 1) ? xv.y
                               : (kk == 2) ? xv.z : xv.w;
                const float* wp = wbase + (k4 * 4 + kk) * 256;  // wave-uniform
#pragma unroll
                for (int q = 0; q < 16; ++q)
                    acc[q] = fmaf(xk, wp[q], acc[q]);
            }
        }
        if (c < 7) {
            __syncthreads();   // all waves done reading xs[buf^1] (chunk c-1)
#pragma unroll
            for (int m = 0; m < 4; ++m)
                *(float4*)&xs[buf ^ 1][tk][kq * 16 + m * 4] = st[m];
            if (c < 6) {
#pragma unroll
                for (int m = 0; m < 4; ++m)
                    st[m] = *(const float4*)(gsrc + (c + 2) * 64 + m * 4);
            }
            __syncthreads();   // xs[buf^1] ready
        }
    }
    // gelu (exact, matches reference) + dot with this wave's Ws2 chunk
    float v = 0.0f;
#pragma unroll
    for (int q = 0; q < 16; ++q) {
        const float hv = acc[q];
        v = fmaf(0.5f * hv * (1.0f + erff(hv * 0.70710678118f)), Ws2[j0 + q], v);
    }
    red[w][lane] = v;
    __syncthreads();
    if (tid < 64)
        imp_part[hg * 8192 + t0 + tid] =
            (red[0][tid] + red[1][tid]) + (red[2][tid] + red[3][tid]);
}

// ---------------------------------------------------------------------------
// Per-batch exact top-k via radix-select over summed partials, then
// index-ordered tie resolution (matches jax.lax.top_k selected SET).
// One block (1024 thr) per batch. Writes sel[b][i] in {0,1}.
// ---------------------------------------------------------------------------
__global__ __launch_bounds__(1024) void topk_select_k(
    const float* __restrict__ imp_part, const float* __restrict__ bs2,
    unsigned char* __restrict__ sel)
{
    __shared__ unsigned int keys[4096];
    __shared__ unsigned int hist[256];
    __shared__ int chunkscan[64];
    __shared__ unsigned int sh_prefix;
    __shared__ int sh_rem;
    const int b = blockIdx.x, tid = threadIdx.x;
    const int lane = tid & 63, w = tid >> 6;
    const float bs2v = bs2[0];
    for (int i = tid; i < 4096; i += 1024) {
        const int t = b * 4096 + i;
        const float f = (imp_part[t] + imp_part[8192 + t])
                      + (imp_part[16384 + t] + imp_part[24576 + t]) + bs2v;
        const unsigned int u = __float_as_uint(f);
        keys[i] = (u & 0x80000000u) ? ~u : (u | 0x80000000u);  // order-preserving
    }
    if (tid == 0) { sh_prefix = 0u; sh_rem = TOPK_; }
    __syncthreads();
    unsigned int pmask = 0;
    for (int level = 3; level >= 0; --level) {
        const int shb = level * 8;
        const unsigned int prefix = sh_prefix;
        const int remaining = sh_rem;
        if (tid < 256) hist[tid] = 0;
        __syncthreads();
        for (int i = tid; i < 4096; i += 1024) {
            const unsigned int u = keys[i];
            if ((u & pmask) == prefix) atomicAdd(&hist[(u >> shb) & 255u], 1u);
        }
        __syncthreads();
        if (tid < 64) {
            unsigned int v[4];
            int tot = 0;
#pragma unroll
            for (int q = 0; q < 4; ++q) { v[q] = hist[255 - (tid * 4 + q)]; tot += (int)v[q]; }
            int pre = tot;
            for (int off = 1; off < 64; off <<= 1) {
                const int t = __shfl_up(pre, off);
                if (tid >= off) pre += t;
            }
            const unsigned long long bal = __ballot(pre >= remaining);
            const int L = __ffsll((unsigned long long)bal) - 1;
            if (tid == L) {
                int c = pre - tot;
#pragma unroll
                for (int q = 0; q < 4; ++q) {
                    c += (int)v[q];
                    if (c >= remaining) {
                        sh_rem = remaining - (c - (int)v[q]);
                        sh_prefix = prefix | ((unsigned int)(255 - (tid * 4 + q)) << shb);
                        break;
                    }
                }
            }
        }
        __syncthreads();
        pmask |= (255u << shb);
    }
    const unsigned int T = sh_prefix;
    const int need = sh_rem;  // how many == T elements to take (index asc)
#pragma unroll
    for (int q = 0; q < 4; ++q) {
        const int chunk = w * 4 + q;
        const unsigned long long bal = __ballot(keys[chunk * 64 + lane] == T);
        if (lane == 0) chunkscan[chunk] = __popcll(bal);
    }
    __syncthreads();
    if (tid < 64) {
        const int v = chunkscan[tid];
        int pre = v;
        for (int off = 1; off < 64; off <<= 1) {
            const int t = __shfl_up(pre, off);
            if (tid >= off) pre += t;
        }
        chunkscan[tid] = pre - v;  // exclusive prefix
    }
    __syncthreads();
#pragma unroll
    for (int q = 0; q < 4; ++q) {
        const int chunk = w * 4 + q;
        const int i = chunk * 64 + lane;
        const unsigned int u = keys[i];
        const bool eq = (u == T);
        const unsigned long long bal = __ballot(eq);
        const int rank = chunkscan[chunk] + __popcll(bal & ((1ull << lane) - 1ull));
        sel[b * 4096 + i] = (u > T || (eq && rank < need)) ? 1 : 0;
    }
}

// ---------------------------------------------------------------------------
// Union of per-batch selections -> compacted ascending column list + gather
// rowmap. 1 wave.
// ---------------------------------------------------------------------------
__global__ void compact_k(const unsigned char* __restrict__ sel,
                          int* __restrict__ rowmap, int* __restrict__ keffp)
{
    const int lane = threadIdx.x;  // 64 threads = 1 wave
    int base = 0;
    for (int c = 0; c < 64; ++c) {
        const int pos = c * 64 + lane;
        const bool f = (sel[pos] | sel[4096 + pos]) != 0;
        const unsigned long long bal = __ballot(f);
        const int rank = __popcll(bal & ((1ull << lane) - 1ull));
        if (f) {
            const int s = base + rank;
            rowmap[s] = pos;                  // batch 0 token row
            rowmap[KSLOTS_ + s] = 4096 + pos; // batch 1 token row
        }
        base += __popcll(bal);
    }
    for (int s = base + lane; s < KSLOTS_; s += 64) {
        rowmap[s] = 0; rowmap[KSLOTS_ + s] = 4096;  // pad -> token 0 (masked)
    }
    if (lane == 0) keffp[0] = base;
}

// ---------------------------------------------------------------------------
// GEMM: C[M][512] = A[M][512] @ W + bias(col), W given as WT (=W^T), bf16 MFMA.
// Block 256 thr = 4 waves; tile 128x64. Optional row gather (K projection).
// Output: fp32 (Cf) if non-null else bf16 (Cb).
// ---------------------------------------------------------------------------
__global__ __launch_bounds__(256) void gemm_k(
    const ushort_t* __restrict__ A, const ushort_t* __restrict__ WT,
    const float* __restrict__ bias, ushort_t* __restrict__ Cb,
    float* __restrict__ Cf, const int* __restrict__ row_map)
{
    const int K = 512, N = 512;
    const int tid = threadIdx.x, lane = tid & 63, w = tid >> 6;
    const int l15 = lane & 15, l4 = lane >> 4;
    const int m_base = blockIdx.x * 128 + w * 32;
    const int n_base = blockIdx.y * 64;

    const int r0 = m_base + l15;
    const int r1 = m_base + 16 + l15;
    const long ar0 = row_map ? (long)row_map[r0] : (long)r0;
    const long ar1 = row_map ? (long)row_map[r1] : (long)r1;
    const ushort_t* a0p = A + ar0 * K + l4 * 8;
    const ushort_t* a1p = A + ar1 * K + l4 * 8;
    const ushort_t* bp0 = WT + (long)(n_base +  0 + l15) * K + l4 * 8;
    const ushort_t* bp1 = WT + (long)(n_base + 16 + l15) * K + l4 * 8;
    const ushort_t* bp2 = WT + (long)(n_base + 32 + l15) * K + l4 * 8;
    const ushort_t* bp3 = WT + (long)(n_base + 48 + l15) * K + l4 * 8;

    f32x4 acc[2][4] = {};
#pragma unroll 4
    for (int kk = 0; kk < 16; ++kk) {
        const int ko = kk * 32;
        const short8 a0 = *(const short8*)(a0p + ko);
        const short8 a1 = *(const short8*)(a1p + ko);
        const short8 b0 = *(const short8*)(bp0 + ko);
        const short8 b1 = *(const short8*)(bp1 + ko);
        const short8 b2 = *(const short8*)(bp2 + ko);
        const short8 b3 = *(const short8*)(bp3 + ko);
        acc[0][0] = __builtin_amdgcn_mfma_f32_16x16x32_bf16(a0, b0, acc[0][0], 0, 0, 0);
        acc[1][0] = __builtin_amdgcn_mfma_f32_16x16x32_bf16(a1, b0, acc[1][0], 0, 0, 0);
        acc[0][1] = __builtin_amdgcn_mfma_f32_16x16x32_bf16(a0, b1, acc[0][1], 0, 0, 0);
        acc[1][1] = __builtin_amdgcn_mfma_f32_16x16x32_bf16(a1, b1, acc[1][1], 0, 0, 0);
        acc[0][2] = __builtin_amdgcn_mfma_f32_16x16x32_bf16(a0, b2, acc[0][2], 0, 0, 0);
        acc[1][2] = __builtin_amdgcn_mfma_f32_16x16x32_bf16(a1, b2, acc[1][2], 0, 0, 0);
        acc[0][3] = __builtin_amdgcn_mfma_f32_16x16x32_bf16(a0, b3, acc[0][3], 0, 0, 0);
        acc[1][3] = __builtin_amdgcn_mfma_f32_16x16x32_bf16(a1, b3, acc[1][3], 0, 0, 0);
    }
#pragma unroll
    for (int g = 0; g < 2; ++g)
#pragma unroll
        for (int c = 0; c < 4; ++c) {
            const int col = n_base + c * 16 + l15;
            const float bv = bias[col];
#pragma unroll
            for (int r = 0; r < 4; ++r) {
                const int row = m_base + g * 16 + l4 * 4 + r;
                const float val = acc[g][c][r] + bv;
                if (Cf) Cf[(long)row * N + col] = val;
                else    Cb[(long)row * N + col] = f2bf(val);
            }
        }
}

// ---------------------------------------------------------------------------
// V^T GEMM: vT[d][b*512+slot] = sum_k Wv^T[d][k] * x[rowmap[col]][k] + bv[d].
// A = WvT (rows = d, no gather); B cols = gathered token rows of xb.
// M = 512 (d), N = 1024 (b,slot). Output directly in attn's V layout.
// ---------------------------------------------------------------------------
__global__ __launch_bounds__(256) void gemm_vT_k(
    const ushort_t* __restrict__ WvT, const ushort_t* __restrict__ xb,
    const float* __restrict__ bias, ushort_t* __restrict__ vT,
    const int* __restrict__ col_map)
{
    const int K = 512, N = 1024;
    const int tid = threadIdx.x, lane = tid & 63, w = tid >> 6;
    const int l15 = lane & 15, l4 = lane >> 4;
    const int m_base = blockIdx.x * 128 + w * 32;   // d
    const int n_base = blockIdx.y * 64;             // b*512+slot

    const ushort_t* a0p = WvT + (long)(m_base + l15) * K + l4 * 8;
    const ushort_t* a1p = WvT + (long)(m_base + 16 + l15) * K + l4 * 8;
    const long c0 = col_map[n_base +  0 + l15];
    const long c1 = col_map[n_base + 16 + l15];
    const long c2 = col_map[n_base + 32 + l15];
    const long c3 = col_map[n_base + 48 + l15];
    const ushort_t* bp0 = xb + c0 * K + l4 * 8;
    const ushort_t* bp1 = xb + c1 * K + l4 * 8;
    const ushort_t* bp2 = xb + c2 * K + l4 * 8;
    const ushort_t* bp3 = xb + c3 * K + l4 * 8;

    f32x4 acc[2][4] = {};
#pragma unroll 4
    for (int kk = 0; kk < 16; ++kk) {
        const int ko = kk * 32;
        const short8 a0 = *(const short8*)(a0p + ko);
        const short8 a1 = *(const short8*)(a1p + ko);
        const short8 b0 = *(const short8*)(bp0 + ko);
        const short8 b1 = *(const short8*)(bp1 + ko);
        const short8 b2 = *(const short8*)(bp2 + ko);
        const short8 b3 = *(const short8*)(bp3 + ko);
        acc[0][0] = __builtin_amdgcn_mfma_f32_16x16x32_bf16(a0, b0, acc[0][0], 0, 0, 0);
        acc[1][0] = __builtin_amdgcn_mfma_f32_16x16x32_bf16(a1, b0, acc[1][0], 0, 0, 0);
        acc[0][1] = __builtin_amdgcn_mfma_f32_16x16x32_bf16(a0, b1, acc[0][1], 0, 0, 0);
        acc[1][1] = __builtin_amdgcn_mfma_f32_16x16x32_bf16(a1, b1, acc[1][1], 0, 0, 0);
        acc[0][2] = __builtin_amdgcn_mfma_f32_16x16x32_bf16(a0, b2, acc[0][2], 0, 0, 0);
        acc[1][2] = __builtin_amdgcn_mfma_f32_16x16x32_bf16(a1, b2, acc[1][2], 0, 0, 0);
        acc[0][3] = __builtin_amdgcn_mfma_f32_16x16x32_bf16(a0, b3, acc[0][3], 0, 0, 0);
        acc[1][3] = __builtin_amdgcn_mfma_f32_16x16x32_bf16(a1, b3, acc[1][3], 0, 0, 0);
    }
#pragma unroll
    for (int g = 0; g < 2; ++g)
#pragma unroll
        for (int r = 0; r < 4; ++r) {
            const int row = m_base + g * 16 + l4 * 4 + r;  // d
            const float bv = bias[row];
#pragma unroll
            for (int c = 0; c < 4; ++c) {
                const int col = n_base + c * 16 + l15;
                vT[(long)row * N + col] = f2bf(acc[g][c][r] + bv);
            }
        }
}

// ---------------------------------------------------------------------------
// Flash attention over KSLOTS_ selected keys.
// Grid = B*H*(S/128) = 512 blocks; 4 waves; wave owns 32 q-rows.
// vT layout: [d][b*512+slot].
// ---------------------------------------------------------------------------
__global__ __launch_bounds__(256) void attn_k(
    const ushort_t* __restrict__ q_all, const ushort_t* __restrict__ k_sel,
    const ushort_t* __restrict__ vT, const int* __restrict__ keff_p,
    ushort_t* __restrict__ att)
{
    __shared__ __align__(16) ushort_t Ps[4][32 * 64];
    const int tid = threadIdx.x;
    const int lane = tid & 63, w = tid >> 6;
    const int l15 = lane & 15, l4 = lane >> 4;
    const int bidx = blockIdx.x;
    const int qt = bidx & 31, h = (bidx >> 5) & 7, b = bidx >> 8;
    const int q0 = qt * 128;
    const int keff = keff_p[0];
    ushort_t* ps = Ps[w];

    short8 qf[2][2];
#pragma unroll
    for (int g = 0; g < 2; ++g) {
        const ushort_t* qrow =
            q_all + (long)(b * 4096 + q0 + w * 32 + g * 16 + l15) * 512 + h * 64;
#pragma unroll
        for (int ks = 0; ks < 2; ++ks)
            qf[g][ks] = *(const short8*)(qrow + ks * 32 + l4 * 8);
    }

    f32x4 acc[2][4] = {};
    float mrun[2][4], lrun[2][4];
#pragma unroll
    for (int g = 0; g < 2; ++g)
#pragma unroll
        for (int r = 0; r < 4; ++r) { mrun[g][r] = -3.0e38f; lrun[g][r] = 0.0f; }

#pragma unroll 1
    for (int t = 0; t < KSLOTS_ / 64; ++t) {
        // ---- scores: Q @ K^T for 64 keys ----
        f32x4 s[2][4] = {};
#pragma unroll
        for (int c = 0; c < 4; ++c) {
            const ushort_t* krow =
                k_sel + (long)(b * KSLOTS_ + t * 64 + c * 16 + l15) * 512 + h * 64;
#pragma unroll
            for (int ks = 0; ks < 2; ++ks) {
                const short8 kf = *(const short8*)(krow + ks * 32 + l4 * 8);
                s[0][c] = __builtin_amdgcn_mfma_f32_16x16x32_bf16(qf[0][ks], kf, s[0][c], 0, 0, 0);
                s[1][c] = __builtin_amdgcn_mfma_f32_16x16x32_bf16(qf[1][ks], kf, s[1][c], 0, 0, 0);
            }
        }
        // ---- scale + pad-mask + online softmax ----
#pragma unroll
        for (int g = 0; g < 2; ++g) {
#pragma unroll
            for (int c = 0; c < 4; ++c) {
                const int col = t * 64 + c * 16 + l15;
                const bool valid = col < keff;
#pragma unroll
                for (int r = 0; r < 4; ++r) {
                    const float v = s[g][c][r] * 0.125f;  // HD^-0.5
                    s[g][c][r] = valid ? v : -1.0e30f;
                }
            }
            float sc[4];
#pragma unroll
            for (int r = 0; r < 4; ++r) {
                float rm = fmaxf(fmaxf(s[g][0][r], s[g][1][r]), fmaxf(s[g][2][r], s[g][3][r]));
                rm = fmaxf(rm, __shfl_xor(rm, 1));
                rm = fmaxf(rm, __shfl_xor(rm, 2));
                rm = fmaxf(rm, __shfl_xor(rm, 4));
                rm = fmaxf(rm, __shfl_xor(rm, 8));
                const float mn = fmaxf(mrun[g][r], rm);
                sc[r] = __expf(mrun[g][r] - mn);
                mrun[g][r] = mn;
            }
#pragma unroll
            for (int c = 0; c < 4; ++c)
#pragma unroll
                for (int r = 0; r < 4; ++r)
                    s[g][c][r] = __expf(s[g][c][r] - mrun[g][r]);
#pragma unroll
            for (int r = 0; r < 4; ++r) {
                float rs = s[g][0][r] + s[g][1][r] + s[g][2][r] + s[g][3][r];
                rs += __shfl_xor(rs, 1);
                rs += __shfl_xor(rs, 2);
                rs += __shfl_xor(rs, 4);
                rs += __shfl_xor(rs, 8);
                lrun[g][r] = lrun[g][r] * sc[r] + rs;
#pragma unroll
                for (int cd = 0; cd < 4; ++cd) acc[g][cd][r] *= sc[r];
            }
            // write P (bf16) to per-wave LDS, XOR-swizzled (G4)
#pragma unroll
            for (int c = 0; c < 4; ++c)
#pragma unroll
                for (int r = 0; r < 4; ++r) {
                    const int ql = g * 16 + l4 * 4 + r;
                    const int kl = c * 16 + l15;
                    ps[ql * 64 + (kl ^ ((ql & 7) << 3))] = f2bf(s[g][c][r]);
                }
        }
        // ---- PV: O += P @ V ----
#pragma unroll
        for (int cd = 0; cd < 4; ++cd) {
            const ushort_t* vrow =
                vT + (long)(h * 64 + cd * 16 + l15) * 1024 + b * 512 + t * 64;
#pragma unroll
            for (int ks = 0; ks < 2; ++ks) {
                const short8 vf = *(const short8*)(vrow + ks * 32 + l4 * 8);
#pragma unroll
                for (int g = 0; g < 2; ++g) {
                    const int ql = g * 16 + l15;
                    const short8 pf = *(const short8*)(
                        ps + ql * 64 + ((l4 * 8 + ks * 32) ^ ((ql & 7) << 3)));
                    acc[g][cd] = __builtin_amdgcn_mfma_f32_16x16x32_bf16(pf, vf, acc[g][cd], 0, 0, 0);
                }
            }
        }
    }
    // ---- normalize + store (b, q, h*64+d), bf16 ----
#pragma unroll
    for (int g = 0; g < 2; ++g)
#pragma unroll
        for (int cd = 0; cd < 4; ++cd)
#pragma unroll
            for (int r = 0; r < 4; ++r) {
                const int row = q0 + w * 32 + g * 16 + l4 * 4 + r;
                att[(long)(b * 4096 + row) * 512 + h * 64 + cd * 16 + l15] =
                    f2bf(acc[g][cd][r] / lrun[g][r]);
            }
}

// ---------------------------------------------------------------------------
extern "C" void kernel_launch(void* const* d_in, const int* in_sizes, int n_in,
                              void* d_out, int out_size, void* d_ws, size_t ws_size,
                              hipStream_t stream)
{
    const float* x   = (const float*)d_in[0];
    const float* Wq  = (const float*)d_in[1];
    const float* bq  = (const float*)d_in[2];
    const float* Wk  = (const float*)d_in[3];
    const float* bk  = (const float*)d_in[4];
    const float* Wv  = (const float*)d_in[5];
    const float* bv  = (const float*)d_in[6];
    const float* Wo  = (const float*)d_in[7];
    const float* bo  = (const float*)d_in[8];
    const float* Ws1 = (const float*)d_in[9];
    const float* bs1 = (const float*)d_in[10];
    const float* Ws2 = (const float*)d_in[11];
    const float* bs2 = (const float*)d_in[12];
    // d_in[13] = top_k (=256; structure hardcoded around it)

    char* ws = (char*)d_ws;
    float*          imp_part = (float*)(ws + 0);            // 128 KB (4x8192)
    unsigned char*  sel      = (unsigned char*)(ws + 0x20000); // 8 KB
    int*            keffp    = (int*)(ws + 0x22800);
    int*            rowmap   = (int*)(ws + 0x23000);         // 4 KB
    ushort_t*  WqT    = (ushort_t*)(ws + 0x40000);           // 4 x 512 KB
    ushort_t*  WkT    = WqT + 512 * 512;
    ushort_t*  WvT    = WkT + 512 * 512;
    ushort_t*  WoT    = WvT + 512 * 512;
    ushort_t*  k_sel  = (ushort_t*)(ws + 0x240000);          // 1 MB
    ushort_t*  vT     = (ushort_t*)(ws + 0x340000);          // 1 MB
    ushort_t*  xb     = (ushort_t*)(ws + 0x600000);          // 8 MB (reused as att)
    ushort_t*  att    = xb;                                  // dead after projections
    ushort_t*  q_all  = (ushort_t*)(ws + 0xE00000);          // 8 MB (total ~22 MB)

    const dim3 tblk(256);
    // 1. pack x -> bf16
    pack_bf16_k<<<2048, tblk, 0, stream>>>(x, xb);
    // 2. all 4 weight transposes (fp32 -> bf16), one launch
    transpose4_f32bf_k<<<dim3(16, 16, 4), tblk, 0, stream>>>(
        Wq, Wk, Wv, Wo, WqT, WkT, WvT, WoT);
    // 3. importance partials (fp32 exact)
    imp_k<<<512, tblk, 0, stream>>>(x, Ws1, bs1, Ws2, imp_part);
    // 4. per-batch top-k via radix select (sums partials deterministically)
    topk_select_k<<<2, 1024, 0, stream>>>(imp_part, bs2, sel);
    // 5. union mask -> compacted column list + gather map
    compact_k<<<1, 64, 0, stream>>>(sel, rowmap, keffp);
    // 6. projections: dense Q, gathered K, gathered V (directly transposed)
    gemm_k<<<dim3(64, 8), tblk, 0, stream>>>(xb, WqT, bq, q_all, nullptr, nullptr);
    gemm_k<<<dim3(8, 8),  tblk, 0, stream>>>(xb, WkT, bk, k_sel, nullptr, rowmap);
    gemm_vT_k<<<dim3(4, 16), tblk, 0, stream>>>(WvT, xb, bv, vT, rowmap);
    // 7. sparse flash attention (att overwrites xb region — xb is dead now)
    attn_k<<<512, tblk, 0, stream>>>(q_all, k_sel, vT, keffp, att);
    // 8. output projection -> d_out (fp32)
    gemm_k<<<dim3(64, 8), tblk, 0, stream>>>(att, WoT, bo, nullptr, (float*)d_out, nullptr);
}

// Round 5
// 191.048 us; speedup vs baseline: 1.4842x; 1.1272x over previous
//
#include <hip/hip_runtime.h>
#include <hip/hip_bf16.h>

typedef unsigned short ushort_t;
typedef short short8 __attribute__((ext_vector_type(8)));
typedef float f32x4 __attribute__((ext_vector_type(4)));

#define B_  2
#define S_  4096
#define D_  512
#define H_  8
#define HD_ 64
#define DK_ 256
#define TOPK_ 256
#define KSLOTS_ 512   // 2*TOPK_ slots (union of both batches' top-k)

__device__ __forceinline__ float bf2f(ushort_t u) {
    unsigned int b = ((unsigned int)u) << 16;
    float f;
    __builtin_memcpy(&f, &b, 4);
    return f;
}
__device__ __forceinline__ ushort_t f2bf(float f) {
    unsigned int b;
    __builtin_memcpy(&b, &f, 4);
    b = (b + 0x7FFFu + ((b >> 16) & 1u)) >> 16;
    return (ushort_t)b;
}

// ---------------------------------------------------------------------------
// fp32 -> bf16 hi/lo split pack. hi = RNE(x); lo = RNE(x - hi) (Sterbenz).
// 8 elements/thread, total 8192*512.
// ---------------------------------------------------------------------------
__global__ __launch_bounds__(256) void pack_hilo_k(
    const float* __restrict__ in, ushort_t* __restrict__ hi,
    ushort_t* __restrict__ lo)
{
    const long i = ((long)blockIdx.x * 256 + threadIdx.x) * 8;
    const float4 a = *(const float4*)(in + i);
    const float4 b = *(const float4*)(in + i + 4);
    float v[8] = {a.x, a.y, a.z, a.w, b.x, b.y, b.z, b.w};
    short8 oh, ol;
#pragma unroll
    for (int q = 0; q < 8; ++q) {
        const ushort_t h = f2bf(v[q]);
        oh[q] = (short)h;
        ol[q] = (short)f2bf(v[q] - bf2f(h));
    }
    *(short8*)(hi + i) = oh;
    *(short8*)(lo + i) = ol;
}

// ---------------------------------------------------------------------------
// Fused transpose of the 4 weight matrices fp32 -> bf16 (blockIdx.z selects).
// out[C][R] = bf16(in[R][C]), 512x512 each.
// ---------------------------------------------------------------------------
__global__ __launch_bounds__(256) void transpose4_f32bf_k(
    const float* __restrict__ W0, const float* __restrict__ W1,
    const float* __restrict__ W2, const float* __restrict__ W3,
    ushort_t* __restrict__ O0, ushort_t* __restrict__ O1,
    ushort_t* __restrict__ O2, ushort_t* __restrict__ O3)
{
    const int z = blockIdx.z;
    const float* in = (z == 0) ? W0 : (z == 1) ? W1 : (z == 2) ? W2 : W3;
    ushort_t*   out = (z == 0) ? O0 : (z == 1) ? O1 : (z == 2) ? O2 : O3;
    __shared__ float tile[32][33];
    const int tx = threadIdx.x & 31, ty = threadIdx.x >> 5;  // 32 x 8
    const int c0 = blockIdx.x * 32, r0 = blockIdx.y * 32;
#pragma unroll
    for (int i = 0; i < 32; i += 8)
        tile[ty + i][tx] = in[(long)(r0 + ty + i) * 512 + c0 + tx];
    __syncthreads();
#pragma unroll
    for (int i = 0; i < 32; i += 8)
        out[(long)(c0 + ty + i) * 512 + r0 + tx] = f2bf(tile[tx][ty + i]);
}

// ---------------------------------------------------------------------------
// Ws1 (512x256 fp32) -> Ws1^T hi/lo bf16 (256x512 each). Grid (8,16).
// ---------------------------------------------------------------------------
__global__ __launch_bounds__(256) void transpose_ws1_hilo_k(
    const float* __restrict__ W, ushort_t* __restrict__ hi,
    ushort_t* __restrict__ lo)
{
    __shared__ float tile[32][33];
    const int tx = threadIdx.x & 31, ty = threadIdx.x >> 5;
    const int c0 = blockIdx.x * 32, r0 = blockIdx.y * 32;
#pragma unroll
    for (int i = 0; i < 32; i += 8)
        tile[ty + i][tx] = W[(long)(r0 + ty + i) * 256 + c0 + tx];
    __syncthreads();
#pragma unroll
    for (int i = 0; i < 32; i += 8) {
        const float v = tile[tx][ty + i];
        const ushort_t h = f2bf(v);
        const long o = (long)(c0 + ty + i) * 512 + r0 + tx;
        hi[o] = h;
        lo[o] = f2bf(v - bf2f(h));
    }
}

// ---------------------------------------------------------------------------
// imp via hi/lo bf16 MFMA (error ~1e-5 vs fp32, << top-k spacing ~2e-3):
// h = xhi@Whi + xhi@Wlo + xlo@Whi + bs1 (fp32 acc); imp = gelu(h) @ Ws2.
// bs2 omitted (monotonic shift, selection-invariant).
// Grid 256 blocks: 32 tok x 256 j each; wave w owns 32 tok x 64 j.
// ---------------------------------------------------------------------------
__global__ __launch_bounds__(256) void imp_mfma_k(
    const ushort_t* __restrict__ xhi, const ushort_t* __restrict__ xlo,
    const ushort_t* __restrict__ w1hi, const ushort_t* __restrict__ w1lo,
    const float* __restrict__ bs1, const float* __restrict__ Ws2,
    float* __restrict__ imp)
{
    __shared__ float red[4][32];
    const int tid = threadIdx.x, lane = tid & 63, w = tid >> 6;
    const int l15 = lane & 15, l4 = lane >> 4;
    const int tok0 = blockIdx.x * 32;
    const int j0 = w * 64;

    const ushort_t* a0h = xhi + (long)(tok0 + l15) * 512 + l4 * 8;
    const ushort_t* a1h = a0h + 16 * 512;
    const ushort_t* a0l = xlo + (long)(tok0 + l15) * 512 + l4 * 8;
    const ushort_t* a1l = a0l + 16 * 512;
    const ushort_t* bh0 = w1hi + (long)(j0 + l15) * 512 + l4 * 8;
    const ushort_t* bl0 = w1lo + (long)(j0 + l15) * 512 + l4 * 8;

    f32x4 acc[2][4];
#pragma unroll
    for (int c = 0; c < 4; ++c) {
        const float bv = bs1[j0 + c * 16 + l15];
#pragma unroll
        for (int g = 0; g < 2; ++g)
#pragma unroll
            for (int r = 0; r < 4; ++r) acc[g][c][r] = bv;
    }

#pragma unroll 2
    for (int kk = 0; kk < 16; ++kk) {
        const int ko = kk * 32;
        const short8 A0 = *(const short8*)(a0h + ko);
        const short8 A1 = *(const short8*)(a1h + ko);
        const short8 L0 = *(const short8*)(a0l + ko);
        const short8 L1 = *(const short8*)(a1l + ko);
#pragma unroll
        for (int c = 0; c < 4; ++c) {
            const short8 Bh = *(const short8*)(bh0 + c * (16 * 512) + ko);
            const short8 Bl = *(const short8*)(bl0 + c * (16 * 512) + ko);
            acc[0][c] = __builtin_amdgcn_mfma_f32_16x16x32_bf16(A0, Bh, acc[0][c], 0, 0, 0);
            acc[1][c] = __builtin_amdgcn_mfma_f32_16x16x32_bf16(A1, Bh, acc[1][c], 0, 0, 0);
            acc[0][c] = __builtin_amdgcn_mfma_f32_16x16x32_bf16(A0, Bl, acc[0][c], 0, 0, 0);
            acc[1][c] = __builtin_amdgcn_mfma_f32_16x16x32_bf16(A1, Bl, acc[1][c], 0, 0, 0);
            acc[0][c] = __builtin_amdgcn_mfma_f32_16x16x32_bf16(L0, Bh, acc[0][c], 0, 0, 0);
            acc[1][c] = __builtin_amdgcn_mfma_f32_16x16x32_bf16(L1, Bh, acc[1][c], 0, 0, 0);
        }
    }

    // epilogue: gelu (exact erf, fp32) * Ws2, row-reduce
    float ws2c[4];
#pragma unroll
    for (int c = 0; c < 4; ++c) ws2c[c] = Ws2[j0 + c * 16 + l15];
#pragma unroll
    for (int g = 0; g < 2; ++g)
#pragma unroll
        for (int r = 0; r < 4; ++r) {
            float p = 0.0f;
#pragma unroll
            for (int c = 0; c < 4; ++c) {
                const float hv = acc[g][c][r];
                p = fmaf(0.5f * hv * (1.0f + erff(hv * 0.70710678118f)), ws2c[c], p);
            }
            p += __shfl_xor(p, 1); p += __shfl_xor(p, 2);
            p += __shfl_xor(p, 4); p += __shfl_xor(p, 8);
            if (l15 == 0) red[w][g * 16 + l4 * 4 + r] = p;
        }
    __syncthreads();
    if (tid < 32)
        imp[tok0 + tid] = (red[0][tid] + red[1][tid]) + (red[2][tid] + red[3][tid]);
}

// ---------------------------------------------------------------------------
// Per-batch exact top-k via radix-select, then index-ordered tie resolution
// (matches jax.lax.top_k selected SET). One block (1024 thr) per batch.
// ---------------------------------------------------------------------------
__global__ __launch_bounds__(1024) void topk_select_k(
    const float* __restrict__ imp, unsigned char* __restrict__ sel)
{
    __shared__ unsigned int keys[4096];
    __shared__ unsigned int hist[256];
    __shared__ int chunkscan[64];
    __shared__ unsigned int sh_prefix;
    __shared__ int sh_rem;
    const int b = blockIdx.x, tid = threadIdx.x;
    const int lane = tid & 63, w = tid >> 6;
    for (int i = tid; i < 4096; i += 1024) {
        const unsigned int u = __float_as_uint(imp[b * 4096 + i]);
        keys[i] = (u & 0x80000000u) ? ~u : (u | 0x80000000u);  // order-preserving
    }
    if (tid == 0) { sh_prefix = 0u; sh_rem = TOPK_; }
    __syncthreads();
    unsigned int pmask = 0;
    for (int level = 3; level >= 0; --level) {
        const int shb = level * 8;
        const unsigned int prefix = sh_prefix;
        const int remaining = sh_rem;
        if (tid < 256) hist[tid] = 0;
        __syncthreads();
        for (int i = tid; i < 4096; i += 1024) {
            const unsigned int u = keys[i];
            if ((u & pmask) == prefix) atomicAdd(&hist[(u >> shb) & 255u], 1u);
        }
        __syncthreads();
        if (tid < 64) {
            unsigned int v[4];
            int tot = 0;
#pragma unroll
            for (int q = 0; q < 4; ++q) { v[q] = hist[255 - (tid * 4 + q)]; tot += (int)v[q]; }
            int pre = tot;
            for (int off = 1; off < 64; off <<= 1) {
                const int t = __shfl_up(pre, off);
                if (tid >= off) pre += t;
            }
            const unsigned long long bal = __ballot(pre >= remaining);
            const int L = __ffsll((unsigned long long)bal) - 1;
            if (tid == L) {
                int c = pre - tot;
#pragma unroll
                for (int q = 0; q < 4; ++q) {
                    c += (int)v[q];
                    if (c >= remaining) {
                        sh_rem = remaining - (c - (int)v[q]);
                        sh_prefix = prefix | ((unsigned int)(255 - (tid * 4 + q)) << shb);
                        break;
                    }
                }
            }
        }
        __syncthreads();
        pmask |= (255u << shb);
    }
    const unsigned int T = sh_prefix;
    const int need = sh_rem;  // how many == T elements to take (index asc)
#pragma unroll
    for (int q = 0; q < 4; ++q) {
        const int chunk = w * 4 + q;
        const unsigned long long bal = __ballot(keys[chunk * 64 + lane] == T);
        if (lane == 0) chunkscan[chunk] = __popcll(bal);
    }
    __syncthreads();
    if (tid < 64) {
        const int v = chunkscan[tid];
        int pre = v;
        for (int off = 1; off < 64; off <<= 1) {
            const int t = __shfl_up(pre, off);
            if (tid >= off) pre += t;
        }
        chunkscan[tid] = pre - v;  // exclusive prefix
    }
    __syncthreads();
#pragma unroll
    for (int q = 0; q < 4; ++q) {
        const int chunk = w * 4 + q;
        const int i = chunk * 64 + lane;
        const unsigned int u = keys[i];
        const bool eq = (u == T);
        const unsigned long long bal = __ballot(eq);
        const int rank = chunkscan[chunk] + __popcll(bal & ((1ull << lane) - 1ull));
        sel[b * 4096 + i] = (u > T || (eq && rank < need)) ? 1 : 0;
    }
}

// ---------------------------------------------------------------------------
// Union of per-batch selections -> compacted ascending column list + gather
// rowmap. 1 wave.
// ---------------------------------------------------------------------------
__global__ void compact_k(const unsigned char* __restrict__ sel,
                          int* __restrict__ rowmap, int* __restrict__ keffp)
{
    const int lane = threadIdx.x;  // 64 threads = 1 wave
    int base = 0;
    for (int c = 0; c < 64; ++c) {
        const int pos = c * 64 + lane;
        const bool f = (sel[pos] | sel[4096 + pos]) != 0;
        const unsigned long long bal = __ballot(f);
        const int rank = __popcll(bal & ((1ull << lane) - 1ull));
        if (f) {
            const int s = base + rank;
            rowmap[s] = pos;                  // batch 0 token row
            rowmap[KSLOTS_ + s] = 4096 + pos; // batch 1 token row
        }
        base += __popcll(bal);
    }
    for (int s = base + lane; s < KSLOTS_; s += 64) {
        rowmap[s] = 0; rowmap[KSLOTS_ + s] = 4096;  // pad -> token 0 (masked)
    }
    if (lane == 0) keffp[0] = base;
}

// ---------------------------------------------------------------------------
// GEMM: C[M][512] = A[M][512] @ W + bias(col), W given as WT (=W^T), bf16 MFMA.
// Block 256 thr = 4 waves; tile 128x64. Optional row gather (K projection).
// Output: fp32 (Cf) if non-null else bf16 (Cb).
// ---------------------------------------------------------------------------
__global__ __launch_bounds__(256) void gemm_k(
    const ushort_t* __restrict__ A, const ushort_t* __restrict__ WT,
    const float* __restrict__ bias, ushort_t* __restrict__ Cb,
    float* __restrict__ Cf, const int* __restrict__ row_map)
{
    const int K = 512, N = 512;
    const int tid = threadIdx.x, lane = tid & 63, w = tid >> 6;
    const int l15 = lane & 15, l4 = lane >> 4;
    const int m_base = blockIdx.x * 128 + w * 32;
    const int n_base = blockIdx.y * 64;

    const int r0 = m_base + l15;
    const int r1 = m_base + 16 + l15;
    const long ar0 = row_map ? (long)row_map[r0] : (long)r0;
    const long ar1 = row_map ? (long)row_map[r1] : (long)r1;
    const ushort_t* a0p = A + ar0 * K + l4 * 8;
    const ushort_t* a1p = A + ar1 * K + l4 * 8;
    const ushort_t* bp0 = WT + (long)(n_base +  0 + l15) * K + l4 * 8;
    const ushort_t* bp1 = WT + (long)(n_base + 16 + l15) * K + l4 * 8;
    const ushort_t* bp2 = WT + (long)(n_base + 32 + l15) * K + l4 * 8;
    const ushort_t* bp3 = WT + (long)(n_base + 48 + l15) * K + l4 * 8;

    f32x4 acc[2][4] = {};
#pragma unroll 4
    for (int kk = 0; kk < 16; ++kk) {
        const int ko = kk * 32;
        const short8 a0 = *(const short8*)(a0p + ko);
        const short8 a1 = *(const short8*)(a1p + ko);
        const short8 b0 = *(const short8*)(bp0 + ko);
        const short8 b1 = *(const short8*)(bp1 + ko);
        const short8 b2 = *(const short8*)(bp2 + ko);
        const short8 b3 = *(const short8*)(bp3 + ko);
        acc[0][0] = __builtin_amdgcn_mfma_f32_16x16x32_bf16(a0, b0, acc[0][0], 0, 0, 0);
        acc[1][0] = __builtin_amdgcn_mfma_f32_16x16x32_bf16(a1, b0, acc[1][0], 0, 0, 0);
        acc[0][1] = __builtin_amdgcn_mfma_f32_16x16x32_bf16(a0, b1, acc[0][1], 0, 0, 0);
        acc[1][1] = __builtin_amdgcn_mfma_f32_16x16x32_bf16(a1, b1, acc[1][1], 0, 0, 0);
        acc[0][2] = __builtin_amdgcn_mfma_f32_16x16x32_bf16(a0, b2, acc[0][2], 0, 0, 0);
        acc[1][2] = __builtin_amdgcn_mfma_f32_16x16x32_bf16(a1, b2, acc[1][2], 0, 0, 0);
        acc[0][3] = __builtin_amdgcn_mfma_f32_16x16x32_bf16(a0, b3, acc[0][3], 0, 0, 0);
        acc[1][3] = __builtin_amdgcn_mfma_f32_16x16x32_bf16(a1, b3, acc[1][3], 0, 0, 0);
    }
#pragma unroll
    for (int g = 0; g < 2; ++g)
#pragma unroll
        for (int c = 0; c < 4; ++c) {
            const int col = n_base + c * 16 + l15;
            const float bv = bias[col];
#pragma unroll
            for (int r = 0; r < 4; ++r) {
                const int row = m_base + g * 16 + l4 * 4 + r;
                const float val = acc[g][c][r] + bv;
                if (Cf) Cf[(long)row * N + col] = val;
                else    Cb[(long)row * N + col] = f2bf(val);
            }
        }
}

// ---------------------------------------------------------------------------
// V^T GEMM: vT[d][b*512+slot] = sum_k Wv^T[d][k] * x[rowmap[col]][k] + bv[d].
// ---------------------------------------------------------------------------
__global__ __launch_bounds__(256) void gemm_vT_k(
    const ushort_t* __restrict__ WvT, const ushort_t* __restrict__ xb,
    const float* __restrict__ bias, ushort_t* __restrict__ vT,
    const int* __restrict__ col_map)
{
    const int K = 512, N = 1024;
    const int tid = threadIdx.x, lane = tid & 63, w = tid >> 6;
    const int l15 = lane & 15, l4 = lane >> 4;
    const int m_base = blockIdx.x * 128 + w * 32;   // d
    const int n_base = blockIdx.y * 64;             // b*512+slot

    const ushort_t* a0p = WvT + (long)(m_base + l15) * K + l4 * 8;
    const ushort_t* a1p = WvT + (long)(m_base + 16 + l15) * K + l4 * 8;
    const long c0 = col_map[n_base +  0 + l15];
    const long c1 = col_map[n_base + 16 + l15];
    const long c2 = col_map[n_base + 32 + l15];
    const long c3 = col_map[n_base + 48 + l15];
    const ushort_t* bp0 = xb + c0 * K + l4 * 8;
    const ushort_t* bp1 = xb + c1 * K + l4 * 8;
    const ushort_t* bp2 = xb + c2 * K + l4 * 8;
    const ushort_t* bp3 = xb + c3 * K + l4 * 8;

    f32x4 acc[2][4] = {};
#pragma unroll 4
    for (int kk = 0; kk < 16; ++kk) {
        const int ko = kk * 32;
        const short8 a0 = *(const short8*)(a0p + ko);
        const short8 a1 = *(const short8*)(a1p + ko);
        const short8 b0 = *(const short8*)(bp0 + ko);
        const short8 b1 = *(const short8*)(bp1 + ko);
        const short8 b2 = *(const short8*)(bp2 + ko);
        const short8 b3 = *(const short8*)(bp3 + ko);
        acc[0][0] = __builtin_amdgcn_mfma_f32_16x16x32_bf16(a0, b0, acc[0][0], 0, 0, 0);
        acc[1][0] = __builtin_amdgcn_mfma_f32_16x16x32_bf16(a1, b0, acc[1][0], 0, 0, 0);
        acc[0][1] = __builtin_amdgcn_mfma_f32_16x16x32_bf16(a0, b1, acc[0][1], 0, 0, 0);
        acc[1][1] = __builtin_amdgcn_mfma_f32_16x16x32_bf16(a1, b1, acc[1][1], 0, 0, 0);
        acc[0][2] = __builtin_amdgcn_mfma_f32_16x16x32_bf16(a0, b2, acc[0][2], 0, 0, 0);
        acc[1][2] = __builtin_amdgcn_mfma_f32_16x16x32_bf16(a1, b2, acc[1][2], 0, 0, 0);
        acc[0][3] = __builtin_amdgcn_mfma_f32_16x16x32_bf16(a0, b3, acc[0][3], 0, 0, 0);
        acc[1][3] = __builtin_amdgcn_mfma_f32_16x16x32_bf16(a1, b3, acc[1][3], 0, 0, 0);
    }
#pragma unroll
    for (int g = 0; g < 2; ++g)
#pragma unroll
        for (int r = 0; r < 4; ++r) {
            const int row = m_base + g * 16 + l4 * 4 + r;  // d
            const float bv = bias[row];
#pragma unroll
            for (int c = 0; c < 4; ++c) {
                const int col = n_base + c * 16 + l15;
                vT[(long)row * N + col] = f2bf(acc[g][c][r] + bv);
            }
        }
}

// ---------------------------------------------------------------------------
// Flash attention over KSLOTS_ selected keys.
// Grid = B*H*(S/128) = 512 blocks; 4 waves; wave owns 32 q-rows.
// vT layout: [d][b*512+slot].
// ---------------------------------------------------------------------------
__global__ __launch_bounds__(256) void attn_k(
    const ushort_t* __restrict__ q_all, const ushort_t* __restrict__ k_sel,
    const ushort_t* __restrict__ vT, const int* __restrict__ keff_p,
    ushort_t* __restrict__ att)
{
    __shared__ __align__(16) ushort_t Ps[4][32 * 64];
    const int tid = threadIdx.x;
    const int lane = tid & 63, w = tid >> 6;
    const int l15 = lane & 15, l4 = lane >> 4;
    const int bidx = blockIdx.x;
    const int qt = bidx & 31, h = (bidx >> 5) & 7, b = bidx >> 8;
    const int q0 = qt * 128;
    const int keff = keff_p[0];
    ushort_t* ps = Ps[w];

    short8 qf[2][2];
#pragma unroll
    for (int g = 0; g < 2; ++g) {
        const ushort_t* qrow =
            q_all + (long)(b * 4096 + q0 + w * 32 + g * 16 + l15) * 512 + h * 64;
#pragma unroll
        for (int ks = 0; ks < 2; ++ks)
            qf[g][ks] = *(const short8*)(qrow + ks * 32 + l4 * 8);
    }

    f32x4 acc[2][4] = {};
    float mrun[2][4], lrun[2][4];
#pragma unroll
    for (int g = 0; g < 2; ++g)
#pragma unroll
        for (int r = 0; r < 4; ++r) { mrun[g][r] = -3.0e38f; lrun[g][r] = 0.0f; }

#pragma unroll 1
    for (int t = 0; t < KSLOTS_ / 64; ++t) {
        // ---- scores: Q @ K^T for 64 keys ----
        f32x4 s[2][4] = {};
#pragma unroll
        for (int c = 0; c < 4; ++c) {
            const ushort_t* krow =
                k_sel + (long)(b * KSLOTS_ + t * 64 + c * 16 + l15) * 512 + h * 64;
#pragma unroll
            for (int ks = 0; ks < 2; ++ks) {
                const short8 kf = *(const short8*)(krow + ks * 32 + l4 * 8);
                s[0][c] = __builtin_amdgcn_mfma_f32_16x16x32_bf16(qf[0][ks], kf, s[0][c], 0, 0, 0);
                s[1][c] = __builtin_amdgcn_mfma_f32_16x16x32_bf16(qf[1][ks], kf, s[1][c], 0, 0, 0);
            }
        }
        // ---- scale + pad-mask + online softmax ----
#pragma unroll
        for (int g = 0; g < 2; ++g) {
#pragma unroll
            for (int c = 0; c < 4; ++c) {
                const int col = t * 64 + c * 16 + l15;
                const bool valid = col < keff;
#pragma unroll
                for (int r = 0; r < 4; ++r) {
                    const float v = s[g][c][r] * 0.125f;  // HD^-0.5
                    s[g][c][r] = valid ? v : -1.0e30f;
                }
            }
            float sc[4];
#pragma unroll
            for (int r = 0; r < 4; ++r) {
                float rm = fmaxf(fmaxf(s[g][0][r], s[g][1][r]), fmaxf(s[g][2][r], s[g][3][r]));
                rm = fmaxf(rm, __shfl_xor(rm, 1));
                rm = fmaxf(rm, __shfl_xor(rm, 2));
                rm = fmaxf(rm, __shfl_xor(rm, 4));
                rm = fmaxf(rm, __shfl_xor(rm, 8));
                const float mn = fmaxf(mrun[g][r], rm);
                sc[r] = __expf(mrun[g][r] - mn);
                mrun[g][r] = mn;
            }
#pragma unroll
            for (int c = 0; c < 4; ++c)
#pragma unroll
                for (int r = 0; r < 4; ++r)
                    s[g][c][r] = __expf(s[g][c][r] - mrun[g][r]);
#pragma unroll
            for (int r = 0; r < 4; ++r) {
                float rs = s[g][0][r] + s[g][1][r] + s[g][2][r] + s[g][3][r];
                rs += __shfl_xor(rs, 1);
                rs += __shfl_xor(rs, 2);
                rs += __shfl_xor(rs, 4);
                rs += __shfl_xor(rs, 8);
                lrun[g][r] = lrun[g][r] * sc[r] + rs;
#pragma unroll
                for (int cd = 0; cd < 4; ++cd) acc[g][cd][r] *= sc[r];
            }
            // write P (bf16) to per-wave LDS, XOR-swizzled (G4)
#pragma unroll
            for (int c = 0; c < 4; ++c)
#pragma unroll
                for (int r = 0; r < 4; ++r) {
                    const int ql = g * 16 + l4 * 4 + r;
                    const int kl = c * 16 + l15;
                    ps[ql * 64 + (kl ^ ((ql & 7) << 3))] = f2bf(s[g][c][r]);
                }
        }
        // ---- PV: O += P @ V ----
#pragma unroll
        for (int cd = 0; cd < 4; ++cd) {
            const ushort_t* vrow =
                vT + (long)(h * 64 + cd * 16 + l15) * 1024 + b * 512 + t * 64;
#pragma unroll
            for (int ks = 0; ks < 2; ++ks) {
                const short8 vf = *(const short8*)(vrow + ks * 32 + l4 * 8);
#pragma unroll
                for (int g = 0; g < 2; ++g) {
                    const int ql = g * 16 + l15;
                    const short8 pf = *(const short8*)(
                        ps + ql * 64 + ((l4 * 8 + ks * 32) ^ ((ql & 7) << 3)));
                    acc[g][cd] = __builtin_amdgcn_mfma_f32_16x16x32_bf16(pf, vf, acc[g][cd], 0, 0, 0);
                }
            }
        }
    }
    // ---- normalize + store (b, q, h*64+d), bf16 ----
#pragma unroll
    for (int g = 0; g < 2; ++g)
#pragma unroll
        for (int cd = 0; cd < 4; ++cd)
#pragma unroll
            for (int r = 0; r < 4; ++r) {
                const int row = q0 + w * 32 + g * 16 + l4 * 4 + r;
                att[(long)(b * 4096 + row) * 512 + h * 64 + cd * 16 + l15] =
                    f2bf(acc[g][cd][r] / lrun[g][r]);
            }
}

// ---------------------------------------------------------------------------
extern "C" void kernel_launch(void* const* d_in, const int* in_sizes, int n_in,
                              void* d_out, int out_size, void* d_ws, size_t ws_size,
                              hipStream_t stream)
{
    const float* x   = (const float*)d_in[0];
    const float* Wq  = (const float*)d_in[1];
    const float* bq  = (const float*)d_in[2];
    const float* Wk  = (const float*)d_in[3];
    const float* bk  = (const float*)d_in[4];
    const float* Wv  = (const float*)d_in[5];
    const float* bv  = (const float*)d_in[6];
    const float* Wo  = (const float*)d_in[7];
    const float* bo  = (const float*)d_in[8];
    const float* Ws1 = (const float*)d_in[9];
    const float* bs1 = (const float*)d_in[10];
    const float* Ws2 = (const float*)d_in[11];
    // d_in[12] = bs2 (selection-invariant, unused), d_in[13] = top_k (=256)

    char* ws = (char*)d_ws;
    float*          imp    = (float*)(ws + 0);              // 32 KB
    unsigned char*  sel    = (unsigned char*)(ws + 0x8000); // 8 KB
    int*            keffp  = (int*)(ws + 0xA800);
    int*            rowmap = (int*)(ws + 0xB000);           // 4 KB
    ushort_t*  WqT    = (ushort_t*)(ws + 0x40000);          // 4 x 512 KB
    ushort_t*  WkT    = WqT + 512 * 512;
    ushort_t*  WvT    = WkT + 512 * 512;
    ushort_t*  WoT    = WvT + 512 * 512;
    ushort_t*  k_sel  = (ushort_t*)(ws + 0x240000);         // 1 MB
    ushort_t*  vT     = (ushort_t*)(ws + 0x340000);         // 1 MB
    ushort_t*  w1hi   = (ushort_t*)(ws + 0x440000);         // 256 KB
    ushort_t*  w1lo   = (ushort_t*)(ws + 0x480000);         // 256 KB
    ushort_t*  xb     = (ushort_t*)(ws + 0x600000);         // 8 MB (= x_hi; reused as att)
    ushort_t*  att    = xb;                                 // dead after projections
    ushort_t*  xlo    = (ushort_t*)(ws + 0xE00000);         // 8 MB (reused as q_all)
    ushort_t*  q_all  = xlo;                                // xlo dead after imp_mfma
    // total ws footprint: 22 MB (same as round 4)

    const dim3 tblk(256);
    // 1. pack x -> bf16 hi/lo
    pack_hilo_k<<<2048, tblk, 0, stream>>>(x, xb, xlo);
    // 2. weight transposes (fp32 -> bf16)
    transpose4_f32bf_k<<<dim3(16, 16, 4), tblk, 0, stream>>>(
        Wq, Wk, Wv, Wo, WqT, WkT, WvT, WoT);
    transpose_ws1_hilo_k<<<dim3(8, 16), tblk, 0, stream>>>(Ws1, w1hi, w1lo);
    // 3. importance via hi/lo MFMA (selection-exact vs fp32)
    imp_mfma_k<<<256, tblk, 0, stream>>>(xb, xlo, w1hi, w1lo, bs1, Ws2, imp);
    // 4. per-batch top-k via radix select
    topk_select_k<<<2, 1024, 0, stream>>>(imp, sel);
    // 5. union mask -> compacted column list + gather map
    compact_k<<<1, 64, 0, stream>>>(sel, rowmap, keffp);
    // 6. projections: dense Q (q_all overwrites xlo — dead), gathered K,
    //    gathered V (directly transposed)
    gemm_k<<<dim3(64, 8), tblk, 0, stream>>>(xb, WqT, bq, q_all, nullptr, nullptr);
    gemm_k<<<dim3(8, 8),  tblk, 0, stream>>>(xb, WkT, bk, k_sel, nullptr, rowmap);
    gemm_vT_k<<<dim3(4, 16), tblk, 0, stream>>>(WvT, xb, bv, vT, rowmap);
    // 7. sparse flash attention (att overwrites xb region — xb is dead now)
    attn_k<<<512, tblk, 0, stream>>>(q_all, k_sel, vT, keffp, att);
    // 8. output projection -> d_out (fp32)
    gemm_k<<<dim3(64, 8), tblk, 0, stream>>>(att, WoT, bo, nullptr, (float*)d_out, nullptr);
}